// Round 1
// baseline (1557.131 us; speedup 1.0000x reference)
//
#include <hip/hip_runtime.h>

#define NN 50000
#define NE 800000
#define D_IN 256
#define D_HID 256
#define D_OUT 128

// ---------------- CSR build ----------------

__global__ void k_count(const int* __restrict__ dst, int* __restrict__ cnt) {
    int e = blockIdx.x * blockDim.x + threadIdx.x;
    if (e < NE) atomicAdd(&cnt[dst[e]], 1);
}

__global__ void k_dinv(const int* __restrict__ cnt, float* __restrict__ dinv) {
    int i = blockIdx.x * blockDim.x + threadIdx.x;
    if (i < NN) dinv[i] = rsqrtf((float)(cnt[i] + 1));  // +1 self-loop
}

// single-block exclusive scan of cnt[0..NN) -> row_off[0..NN]
__global__ __launch_bounds__(1024) void k_scan(const int* __restrict__ cnt,
                                               int* __restrict__ row_off) {
    __shared__ int part[1024];
    const int t = threadIdx.x;
    const int CH = (NN + 1023) / 1024;  // 49
    int base = t * CH;
    int s = 0;
    for (int i = base; i < base + CH && i < NN; ++i) s += cnt[i];
    part[t] = s;
    __syncthreads();
    for (int off = 1; off < 1024; off <<= 1) {
        int v = (t >= off) ? part[t - off] : 0;
        __syncthreads();
        part[t] += v;
        __syncthreads();
    }
    int run = (t == 0) ? 0 : part[t - 1];
    for (int i = base; i < base + CH && i < NN; ++i) {
        row_off[i] = run;
        run += cnt[i];
    }
    if (t == 1023) row_off[NN] = part[1023];
}

__global__ void k_fill(const int* __restrict__ src, const int* __restrict__ dst,
                       const int* __restrict__ row_off, int* __restrict__ cursor,
                       int* __restrict__ csr) {
    int e = blockIdx.x * blockDim.x + threadIdx.x;
    if (e < NE) {
        int d = dst[e];
        int pos = atomicAdd(&cursor[d], 1);
        csr[row_off[d] + pos] = src[e];
    }
}

// ---------------- GEMM: C[M x NC] = (A[M x 256] @ W[256 x NC]) * dinv[row] ----------------

template <int NC>
__global__ __launch_bounds__(256) void k_gemm_scaled(const float* __restrict__ A,
                                                     const float* __restrict__ W,
                                                     const float* __restrict__ dinv,
                                                     float* __restrict__ C) {
    constexpr int NBX = NC / 64;
    const int bx = blockIdx.x % NBX;
    const int by = blockIdx.x / NBX;
    const int t = threadIdx.x;
    const int tx = t & 15, ty = t >> 4;

    __shared__ float sA[16][68];
    __shared__ float sB[16][68];

    float acc[4][4] = {};
    const int row0 = by * 64;

    const int ar = t >> 2, ac4 = (t & 3) * 4;   // A tile: 64 rows x 16 k
    const int br = t >> 4, bc4 = (t & 15) * 4;  // B tile: 16 k x 64 cols

    for (int kt = 0; kt < 256; kt += 16) {
        float4 av = make_float4(0.f, 0.f, 0.f, 0.f);
        int arow = row0 + ar;
        if (arow < NN) av = *(const float4*)&A[(size_t)arow * 256 + kt + ac4];
        float4 bv = *(const float4*)&W[(size_t)(kt + br) * NC + bx * 64 + bc4];

        __syncthreads();
        sA[ac4 + 0][ar] = av.x;
        sA[ac4 + 1][ar] = av.y;
        sA[ac4 + 2][ar] = av.z;
        sA[ac4 + 3][ar] = av.w;
        *(float4*)&sB[br][bc4] = bv;
        __syncthreads();

#pragma unroll
        for (int k = 0; k < 16; ++k) {
            float4 a = *(const float4*)&sA[k][ty * 4];
            float4 b = *(const float4*)&sB[k][tx * 4];
            acc[0][0] += a.x * b.x; acc[0][1] += a.x * b.y; acc[0][2] += a.x * b.z; acc[0][3] += a.x * b.w;
            acc[1][0] += a.y * b.x; acc[1][1] += a.y * b.y; acc[1][2] += a.y * b.z; acc[1][3] += a.y * b.w;
            acc[2][0] += a.z * b.x; acc[2][1] += a.z * b.y; acc[2][2] += a.z * b.z; acc[2][3] += a.z * b.w;
            acc[3][0] += a.w * b.x; acc[3][1] += a.w * b.y; acc[3][2] += a.w * b.z; acc[3][3] += a.w * b.w;
        }
    }

#pragma unroll
    for (int i = 0; i < 4; ++i) {
        int row = row0 + ty * 4 + i;
        if (row < NN) {
            float s = dinv[row];
            float4 o = make_float4(acc[i][0] * s, acc[i][1] * s, acc[i][2] * s, acc[i][3] * s);
            *(float4*)&C[(size_t)row * NC + bx * 64 + tx * 4] = o;
        }
    }
}

// ---------------- Aggregation: out[i] = act(dinv[i]*(hs[i] + sum_nbr hs[s]) + bias) ----------------

template <int DIM, bool RELU>
__global__ __launch_bounds__(256) void k_agg(const float* __restrict__ hs,
                                             const int* __restrict__ row_off,
                                             const int* __restrict__ csr,
                                             const float* __restrict__ dinv,
                                             const float* __restrict__ bias,
                                             float* __restrict__ out, int out_stride) {
    const int wid = threadIdx.x >> 6;
    const int lane = threadIdx.x & 63;
    const int node = blockIdx.x * 4 + wid;
    if (node >= NN) return;

    constexpr int VPL = DIM / 64;  // 4 (256) or 2 (128)

    float acc[VPL];
    {
        const float* p = hs + (size_t)node * DIM + lane * VPL;
        if constexpr (VPL == 4) {
            float4 v = *(const float4*)p;
            acc[0] = v.x; acc[1] = v.y; acc[2] = v.z; acc[3] = v.w;
        } else {
            float2 v = *(const float2*)p;
            acc[0] = v.x; acc[1] = v.y;
        }
    }

    const int s0 = row_off[node], s1 = row_off[node + 1];
    for (int j = s0; j < s1; ++j) {
        int s = csr[j];
        const float* p = hs + (size_t)s * DIM + lane * VPL;
        if constexpr (VPL == 4) {
            float4 v = *(const float4*)p;
            acc[0] += v.x; acc[1] += v.y; acc[2] += v.z; acc[3] += v.w;
        } else {
            float2 v = *(const float2*)p;
            acc[0] += v.x; acc[1] += v.y;
        }
    }

    const float di = dinv[node];
    float res[VPL];
#pragma unroll
    for (int j = 0; j < VPL; ++j) {
        res[j] = di * acc[j] + bias[lane * VPL + j];
        if constexpr (RELU) res[j] = fmaxf(res[j], 0.f);
    }

    float* q = out + (size_t)node * out_stride + lane * VPL;
    if constexpr (VPL == 4) {
        *(float4*)q = make_float4(res[0], res[1], res[2], res[3]);
    } else {
        *(float2*)q = make_float2(res[0], res[1]);
    }
}

// ---------------- Attention fusion ----------------

__global__ __launch_bounds__(256) void k_attn(const float* __restrict__ feats,
                                              const float* __restrict__ attn_w,
                                              const float* __restrict__ attn_b,
                                              float* __restrict__ out) {
    const int wid = threadIdx.x >> 6;
    const int lane = threadIdx.x & 63;
    const int node = blockIdx.x * 4 + wid;
    if (node >= NN) return;

    float2 w = *(const float2*)&attn_w[lane * 2];
    const float* f = feats + (size_t)node * 384;
    float2 f0 = *(const float2*)&f[0 * 128 + lane * 2];
    float2 f1 = *(const float2*)&f[1 * 128 + lane * 2];
    float2 f2 = *(const float2*)&f[2 * 128 + lane * 2];

    float s0 = f0.x * w.x + f0.y * w.y;
    float s1 = f1.x * w.x + f1.y * w.y;
    float s2 = f2.x * w.x + f2.y * w.y;
#pragma unroll
    for (int m = 32; m >= 1; m >>= 1) {
        s0 += __shfl_xor(s0, m);
        s1 += __shfl_xor(s1, m);
        s2 += __shfl_xor(s2, m);
    }
    float bb = attn_b[0];
    s0 += bb; s1 += bb; s2 += bb;
    float mx = fmaxf(s0, fmaxf(s1, s2));
    float e0 = expf(s0 - mx), e1 = expf(s1 - mx), e2 = expf(s2 - mx);
    float inv = 1.f / (e0 + e1 + e2);
    e0 *= inv; e1 *= inv; e2 *= inv;

    float2 o;
    o.x = f0.x * e0 + f1.x * e1 + f2.x * e2;
    o.y = f0.y * e0 + f1.y * e1 + f2.y * e2;
    *(float2*)&out[(size_t)node * 128 + lane * 2] = o;
}

// ---------------- launch ----------------

extern "C" void kernel_launch(void* const* d_in, const int* in_sizes, int n_in,
                              void* d_out, int out_size, void* d_ws, size_t ws_size,
                              hipStream_t stream) {
    const float* x = (const float*)d_in[0];
    const int* edge[3] = {(const int*)d_in[1], (const int*)d_in[2], (const int*)d_in[3]};
    const float* attn_w = (const float*)d_in[16];
    const float* attn_b = (const float*)d_in[17];

    char* ws = (char*)d_ws;
    size_t off = 0;
    auto alloc = [&](size_t bytes) -> void* {
        void* p = ws + off;
        off += (bytes + 255) & ~(size_t)255;
        return p;
    };

    float* dinv   = (float*)alloc(NN * 4);
    int*   cnt    = (int*)alloc(NN * 4);
    int*   cursor = (int*)alloc(NN * 4);
    int*   rowoff = (int*)alloc((NN + 1) * 4);
    int*   csr    = (int*)alloc((size_t)NE * 4);
    float* bufA   = (float*)alloc((size_t)NN * 256 * 4);  // gemm out (scaled)
    float* bufB   = (float*)alloc((size_t)NN * 256 * 4);  // layer-1 activations
    float* feats  = (float*)alloc((size_t)NN * 384 * 4);  // [N,3,128]

    const int EB = (NE + 255) / 256;
    const int NB = (NN + 255) / 256;
    const int RB = (NN + 63) / 64;  // 782 row tiles
    const int WB = (NN + 3) / 4;    // 12500 wave-per-node blocks

    for (int k = 0; k < 3; ++k) {
        const int* esrc = edge[k];
        const int* edst = edge[k] + NE;
        const float* w1 = (const float*)d_in[4 + k * 4 + 0];
        const float* b1 = (const float*)d_in[4 + k * 4 + 1];
        const float* w2 = (const float*)d_in[4 + k * 4 + 2];
        const float* b2 = (const float*)d_in[4 + k * 4 + 3];

        hipMemsetAsync(cnt, 0, NN * 4, stream);
        hipMemsetAsync(cursor, 0, NN * 4, stream);
        k_count<<<EB, 256, 0, stream>>>(edst, cnt);
        k_dinv<<<NB, 256, 0, stream>>>(cnt, dinv);
        k_scan<<<1, 1024, 0, stream>>>(cnt, rowoff);
        k_fill<<<EB, 256, 0, stream>>>(esrc, edst, rowoff, cursor, csr);

        // layer 1: hs = dinv * (x @ w1); h1 = relu(dinv*(hs self+nbrs) + b1)
        k_gemm_scaled<256><<<RB * 4, 256, 0, stream>>>(x, w1, dinv, bufA);
        k_agg<256, true><<<WB, 256, 0, stream>>>(bufA, rowoff, csr, dinv, b1, bufB, 256);

        // layer 2: hs2 = dinv * (h1 @ w2); feat = dinv*(hs2 self+nbrs) + b2
        k_gemm_scaled<128><<<RB * 2, 256, 0, stream>>>(bufB, w2, dinv, bufA);
        k_agg<128, false><<<WB, 256, 0, stream>>>(bufA, rowoff, csr, dinv, b2,
                                                  feats + k * 128, 384);
    }

    k_attn<<<WB, 256, 0, stream>>>(feats, attn_w, attn_b, (float*)d_out);
}

// Round 2
// 1379.494 us; speedup vs baseline: 1.1288x; 1.1288x over previous
//
#include <hip/hip_runtime.h>

#define NN 50000
#define NE 800000

typedef __attribute__((ext_vector_type(8))) short short8;
typedef __attribute__((ext_vector_type(4))) float f32x4;

__device__ __forceinline__ ushort f2bf(float f) {
    unsigned u = __float_as_uint(f);
    unsigned r = (u + 0x7fffu + ((u >> 16) & 1u)) >> 16;
    return (ushort)r;
}
__device__ __forceinline__ float bf2f(ushort h) {
    return __uint_as_float(((unsigned)h) << 16);
}

// ---------------- CSR build ----------------

__global__ void k_count(const int* __restrict__ dst, int* __restrict__ cnt) {
    int e = blockIdx.x * blockDim.x + threadIdx.x;
    if (e < NE) atomicAdd(&cnt[dst[e]], 1);
}

__global__ void k_dinv(const int* __restrict__ cnt, float* __restrict__ dinv) {
    int i = blockIdx.x * blockDim.x + threadIdx.x;
    if (i < NN) dinv[i] = rsqrtf((float)(cnt[i] + 1));  // +1 self-loop
}

__global__ __launch_bounds__(1024) void k_scan(const int* __restrict__ cnt,
                                               int* __restrict__ row_off) {
    __shared__ int part[1024];
    const int t = threadIdx.x;
    const int CH = (NN + 1023) / 1024;  // 49
    int base = t * CH;
    int s = 0;
    for (int i = base; i < base + CH && i < NN; ++i) s += cnt[i];
    part[t] = s;
    __syncthreads();
    for (int off = 1; off < 1024; off <<= 1) {
        int v = (t >= off) ? part[t - off] : 0;
        __syncthreads();
        part[t] += v;
        __syncthreads();
    }
    int run = (t == 0) ? 0 : part[t - 1];
    for (int i = base; i < base + CH && i < NN; ++i) {
        row_off[i] = run;
        run += cnt[i];
    }
    if (t == 1023) row_off[NN] = part[1023];
}

__global__ void k_fill(const int* __restrict__ src, const int* __restrict__ dst,
                       const int* __restrict__ row_off, int* __restrict__ cursor,
                       int* __restrict__ csr) {
    int e = blockIdx.x * blockDim.x + threadIdx.x;
    if (e < NE) {
        int d = dst[e];
        int pos = atomicAdd(&cursor[d], 1);
        csr[row_off[d] + pos] = src[e];
    }
}

// ---------------- conversions ----------------

// x [NN x 256] f32 -> xp [NN x 512] bf16: cols 0..255 = hi, 256..511 = lo
__global__ __launch_bounds__(256) void k_conv_x(const float* __restrict__ x,
                                                ushort* __restrict__ xp) {
    const int wid = threadIdx.x >> 6, lane = threadIdx.x & 63;
    const int row = blockIdx.x * 4 + wid;
    if (row >= NN) return;
    float4 v = *(const float4*)&x[(size_t)row * 256 + lane * 4];
    ushort4 hi, lo;
    hi.x = f2bf(v.x); lo.x = f2bf(v.x - bf2f(hi.x));
    hi.y = f2bf(v.y); lo.y = f2bf(v.y - bf2f(hi.y));
    hi.z = f2bf(v.z); lo.z = f2bf(v.z - bf2f(hi.z));
    hi.w = f2bf(v.w); lo.w = f2bf(v.w - bf2f(hi.w));
    *(ushort4*)&xp[(size_t)row * 512 + lane * 4] = hi;
    *(ushort4*)&xp[(size_t)row * 512 + 256 + lane * 4] = lo;
}

// W [KIN x NOUT] f32 -> BT [NOUT x 3*KIN] bf16: [B_hi; B_hi; B_lo] transposed
template <int KIN, int NOUT>
__global__ __launch_bounds__(256) void k_conv_w(const float* __restrict__ W,
                                                ushort* __restrict__ BT) {
    int idx = blockIdx.x * 256 + threadIdx.x;
    if (idx >= KIN * NOUT) return;
    int k = idx / NOUT, n = idx % NOUT;
    float w = W[idx];
    ushort hi = f2bf(w);
    ushort lo = f2bf(w - bf2f(hi));
    ushort* r = BT + (size_t)n * (3 * KIN);
    r[k] = hi;
    r[KIN + k] = hi;
    r[2 * KIN + k] = lo;
}

// ---------------- bf16x3 MFMA GEMM ----------------
// C[M x N] = (A' @ B') * dinv[row],  A' = [A_hi|A_lo] (AK=512 cols, hi reused
// for k>=512), B'T = [NOUT x 768].  16x16x32 bf16 MFMA, global_load_lds
// staging with XOR-swizzled 16B slots (linear LDS dest + swizzled source +
// swizzled ds_read).

template <int BM, int BN, int N>
__global__ __launch_bounds__((BM / 64) * (BN / 64) * 64) void k_gemm(
    const ushort* __restrict__ A, const ushort* __restrict__ BT,
    const float* __restrict__ dinv, float* __restrict__ C) {
    constexpr int WGN = BN / 64, NW = (BM / 64) * WGN;
    constexpr int K3 = 768, AK = 512, BK = 32;
    __shared__ ushort sA[BM * BK];
    __shared__ ushort sB[BN * BK];
    const int t = threadIdx.x, lane = t & 63, wid = t >> 6;
    const int wm = (wid / WGN) * 64, wn = (wid % WGN) * 64;
    constexpr int NTILES = N / BN;
    const int bm = (int)(blockIdx.x / NTILES) * BM;
    const int bn = (int)(blockIdx.x % NTILES) * BN;

    f32x4 zero = {0.f, 0.f, 0.f, 0.f};
    f32x4 acc[4][4];
#pragma unroll
    for (int m = 0; m < 4; ++m)
#pragma unroll
        for (int n = 0; n < 4; ++n) acc[m][n] = zero;

    constexpr int A_ISS = (BM * BK * 2) / (NW * 1024);
    constexpr int B_ISS = (BN * BK * 2) / (NW * 1024);

    for (int kt = 0; kt < K3; kt += BK) {
        const int akt = (kt >= AK) ? kt - AK : kt;  // A hi-block reuse for 3rd third
        __syncthreads();
#pragma unroll
        for (int i = 0; i < A_ISS; ++i) {
            int off = (wid + i * NW) << 10;
            int la = off + lane * 16;
            int row = la >> 6;
            int slot = (la >> 4) & 3;
            int scol = (slot ^ (row & 3)) << 4;
            int grow = bm + row;
            if (grow > NN - 1) grow = NN - 1;
            const char* ga = (const char*)A + (size_t)grow * (AK * 2) + akt * 2 + scol;
            __builtin_amdgcn_global_load_lds(
                (__attribute__((address_space(1))) const void*)ga,
                (__attribute__((address_space(3))) void*)((char*)sA + off), 16, 0, 0);
        }
#pragma unroll
        for (int i = 0; i < B_ISS; ++i) {
            int off = (wid + i * NW) << 10;
            int la = off + lane * 16;
            int row = la >> 6;
            int slot = (la >> 4) & 3;
            int scol = (slot ^ (row & 3)) << 4;
            const char* ga = (const char*)BT + (size_t)(bn + row) * (K3 * 2) + kt * 2 + scol;
            __builtin_amdgcn_global_load_lds(
                (__attribute__((address_space(1))) const void*)ga,
                (__attribute__((address_space(3))) void*)((char*)sB + off), 16, 0, 0);
        }
        __syncthreads();

        const int s = lane >> 4;
        const int r0 = lane & 15;
        short8 af[4], bf[4];
#pragma unroll
        for (int m = 0; m < 4; ++m) {
            int row = wm + m * 16 + r0;
            af[m] = *(const short8*)((const char*)sA + row * 64 + ((s ^ (row & 3)) << 4));
        }
#pragma unroll
        for (int n = 0; n < 4; ++n) {
            int row = wn + n * 16 + r0;
            bf[n] = *(const short8*)((const char*)sB + row * 64 + ((s ^ (row & 3)) << 4));
        }
#pragma unroll
        for (int m = 0; m < 4; ++m)
#pragma unroll
            for (int n = 0; n < 4; ++n)
                acc[m][n] = __builtin_amdgcn_mfma_f32_16x16x32_bf16(af[m], bf[n],
                                                                    acc[m][n], 0, 0, 0);
    }

    const int cr0 = (lane >> 4) * 4;
    const int cc = lane & 15;
#pragma unroll
    for (int m = 0; m < 4; ++m) {
#pragma unroll
        for (int r = 0; r < 4; ++r) {
            int row = bm + wm + m * 16 + cr0 + r;
            if (row < NN) {
                float dv = dinv[row];
#pragma unroll
                for (int n = 0; n < 4; ++n)
                    C[(size_t)row * N + bn + wn + n * 16 + cc] = acc[m][n][r] * dv;
            }
        }
    }
}

// ---------------- aggregation ----------------

// layer 1: gather 256-d fp32, relu, write bf16 hi|lo [NN x 512]
__global__ __launch_bounds__(256) void k_agg1(const float* __restrict__ hs,
                                              const int* __restrict__ row_off,
                                              const int* __restrict__ csr,
                                              const float* __restrict__ dinv,
                                              const float* __restrict__ bias,
                                              ushort* __restrict__ hp) {
    const int wid = threadIdx.x >> 6;
    const int lane = threadIdx.x & 63;
    const int node = blockIdx.x * 4 + wid;
    if (node >= NN) return;

    float acc[4];
    {
        float4 v = *(const float4*)&hs[(size_t)node * 256 + lane * 4];
        acc[0] = v.x; acc[1] = v.y; acc[2] = v.z; acc[3] = v.w;
    }
    const int s0 = row_off[node], s1 = row_off[node + 1];
    for (int j = s0; j < s1; ++j) {
        int s = csr[j];
        float4 v = *(const float4*)&hs[(size_t)s * 256 + lane * 4];
        acc[0] += v.x; acc[1] += v.y; acc[2] += v.z; acc[3] += v.w;
    }
    const float di = dinv[node];
    ushort4 hi, lo;
    float r0 = fmaxf(di * acc[0] + bias[lane * 4 + 0], 0.f);
    float r1 = fmaxf(di * acc[1] + bias[lane * 4 + 1], 0.f);
    float r2 = fmaxf(di * acc[2] + bias[lane * 4 + 2], 0.f);
    float r3 = fmaxf(di * acc[3] + bias[lane * 4 + 3], 0.f);
    hi.x = f2bf(r0); lo.x = f2bf(r0 - bf2f(hi.x));
    hi.y = f2bf(r1); lo.y = f2bf(r1 - bf2f(hi.y));
    hi.z = f2bf(r2); lo.z = f2bf(r2 - bf2f(hi.z));
    hi.w = f2bf(r3); lo.w = f2bf(r3 - bf2f(hi.w));
    *(ushort4*)&hp[(size_t)node * 512 + lane * 4] = hi;
    *(ushort4*)&hp[(size_t)node * 512 + 256 + lane * 4] = lo;
}

// layer 2: gather 128-d fp32, +bias, write fp32 into feats (stride 384)
__global__ __launch_bounds__(256) void k_agg2(const float* __restrict__ hs,
                                              const int* __restrict__ row_off,
                                              const int* __restrict__ csr,
                                              const float* __restrict__ dinv,
                                              const float* __restrict__ bias,
                                              float* __restrict__ out) {
    const int wid = threadIdx.x >> 6;
    const int lane = threadIdx.x & 63;
    const int node = blockIdx.x * 4 + wid;
    if (node >= NN) return;

    float a0, a1;
    {
        float2 v = *(const float2*)&hs[(size_t)node * 128 + lane * 2];
        a0 = v.x; a1 = v.y;
    }
    const int s0 = row_off[node], s1 = row_off[node + 1];
    for (int j = s0; j < s1; ++j) {
        int s = csr[j];
        float2 v = *(const float2*)&hs[(size_t)s * 128 + lane * 2];
        a0 += v.x; a1 += v.y;
    }
    const float di = dinv[node];
    float2 o;
    o.x = di * a0 + bias[lane * 2 + 0];
    o.y = di * a1 + bias[lane * 2 + 1];
    *(float2*)&out[(size_t)node * 384 + lane * 2] = o;
}

// ---------------- attention fusion ----------------

__global__ __launch_bounds__(256) void k_attn(const float* __restrict__ feats,
                                              const float* __restrict__ attn_w,
                                              const float* __restrict__ attn_b,
                                              float* __restrict__ out) {
    const int wid = threadIdx.x >> 6;
    const int lane = threadIdx.x & 63;
    const int node = blockIdx.x * 4 + wid;
    if (node >= NN) return;

    float2 w = *(const float2*)&attn_w[lane * 2];
    const float* f = feats + (size_t)node * 384;
    float2 f0 = *(const float2*)&f[0 * 128 + lane * 2];
    float2 f1 = *(const float2*)&f[1 * 128 + lane * 2];
    float2 f2 = *(const float2*)&f[2 * 128 + lane * 2];

    float s0 = f0.x * w.x + f0.y * w.y;
    float s1 = f1.x * w.x + f1.y * w.y;
    float s2 = f2.x * w.x + f2.y * w.y;
#pragma unroll
    for (int m = 32; m >= 1; m >>= 1) {
        s0 += __shfl_xor(s0, m);
        s1 += __shfl_xor(s1, m);
        s2 += __shfl_xor(s2, m);
    }
    float bb = attn_b[0];
    s0 += bb; s1 += bb; s2 += bb;
    float mx = fmaxf(s0, fmaxf(s1, s2));
    float e0 = expf(s0 - mx), e1 = expf(s1 - mx), e2 = expf(s2 - mx);
    float inv = 1.f / (e0 + e1 + e2);
    e0 *= inv; e1 *= inv; e2 *= inv;

    float2 o;
    o.x = f0.x * e0 + f1.x * e1 + f2.x * e2;
    o.y = f0.y * e0 + f1.y * e1 + f2.y * e2;
    *(float2*)&out[(size_t)node * 128 + lane * 2] = o;
}

// ---------------- launch ----------------

extern "C" void kernel_launch(void* const* d_in, const int* in_sizes, int n_in,
                              void* d_out, int out_size, void* d_ws, size_t ws_size,
                              hipStream_t stream) {
    const float* x = (const float*)d_in[0];
    const int* edge[3] = {(const int*)d_in[1], (const int*)d_in[2], (const int*)d_in[3]};
    const float* attn_w = (const float*)d_in[16];
    const float* attn_b = (const float*)d_in[17];

    char* ws = (char*)d_ws;
    size_t off = 0;
    auto alloc = [&](size_t bytes) -> void* {
        void* p = ws + off;
        off += (bytes + 255) & ~(size_t)255;
        return p;
    };

    float* dinv   = (float*)alloc(NN * 4);
    int*   cnt    = (int*)alloc(NN * 4);
    int*   cursor = (int*)alloc(NN * 4);
    int*   rowoff = (int*)alloc((NN + 1) * 4);
    int*   csr    = (int*)alloc((size_t)NE * 4);
    ushort* xp    = (ushort*)alloc((size_t)NN * 512 * 2);  // x hi|lo bf16
    ushort* h1p   = (ushort*)alloc((size_t)NN * 512 * 2);  // h1 hi|lo bf16
    float* hs     = (float*)alloc((size_t)NN * 256 * 4);   // gemm out (also hs2)
    float* feats  = (float*)alloc((size_t)NN * 384 * 4);   // [N,3,128]
    ushort* BT1[3], *BT2[3];
    for (int k = 0; k < 3; ++k) {
        BT1[k] = (ushort*)alloc((size_t)256 * 768 * 2);
        BT2[k] = (ushort*)alloc((size_t)128 * 768 * 2);
    }

    const int EB = (NE + 255) / 256;
    const int NB = (NN + 255) / 256;
    const int WB = (NN + 3) / 4;

    k_conv_x<<<WB, 256, 0, stream>>>(x, xp);
    for (int k = 0; k < 3; ++k) {
        const float* w1 = (const float*)d_in[4 + k * 4 + 0];
        const float* w2 = (const float*)d_in[4 + k * 4 + 2];
        k_conv_w<256, 256><<<(256 * 256 + 255) / 256, 256, 0, stream>>>(w1, BT1[k]);
        k_conv_w<256, 128><<<(256 * 128 + 255) / 256, 256, 0, stream>>>(w2, BT2[k]);
    }

    for (int k = 0; k < 3; ++k) {
        const int* esrc = edge[k];
        const int* edst = edge[k] + NE;
        const float* b1 = (const float*)d_in[4 + k * 4 + 1];
        const float* b2 = (const float*)d_in[4 + k * 4 + 3];

        hipMemsetAsync(cnt, 0, NN * 4, stream);
        hipMemsetAsync(cursor, 0, NN * 4, stream);
        k_count<<<EB, 256, 0, stream>>>(edst, cnt);
        k_dinv<<<NB, 256, 0, stream>>>(cnt, dinv);
        k_scan<<<1, 1024, 0, stream>>>(cnt, rowoff);
        k_fill<<<EB, 256, 0, stream>>>(esrc, edst, rowoff, cursor, csr);

        // layer 1: hs = dinv*(x @ w1) via bf16x3 MFMA; agg -> h1 (bf16 hi|lo)
        k_gemm<128, 128, 256><<<391 * 2, 256, 0, stream>>>(xp, BT1[k], dinv, hs);
        k_agg1<<<WB, 256, 0, stream>>>(hs, rowoff, csr, dinv, b1, h1p);

        // layer 2: hs2 = dinv*(h1 @ w2); agg -> feats[:,k,:]
        k_gemm<64, 128, 128><<<782, 128, 0, stream>>>(h1p, BT2[k], dinv, hs);
        k_agg2<<<WB, 256, 0, stream>>>(hs, rowoff, csr, dinv, b2, feats + k * 128);
    }

    k_attn<<<WB, 256, 0, stream>>>(feats, attn_w, attn_b, (float*)d_out);
}

// Round 3
// 1254.661 us; speedup vs baseline: 1.2411x; 1.0995x over previous
//
#include <hip/hip_runtime.h>

#define NN 50000
#define NE 800000

typedef __attribute__((ext_vector_type(8))) short short8;
typedef __attribute__((ext_vector_type(4))) float f32x4;

__device__ __forceinline__ ushort f2bf(float f) {
    unsigned u = __float_as_uint(f);
    unsigned r = (u + 0x7fffu + ((u >> 16) & 1u)) >> 16;
    return (ushort)r;
}
__device__ __forceinline__ float bf2f(ushort h) {
    return __uint_as_float(((unsigned)h) << 16);
}
__device__ __forceinline__ ushort f2h(float f) {
    _Float16 h = (_Float16)f;
    return __builtin_bit_cast(ushort, h);
}
__device__ __forceinline__ float h2f(ushort u) {
    return (float)__builtin_bit_cast(_Float16, u);
}

// ---------------- CSR build ----------------

__global__ void k_count(const int* __restrict__ dst, int* __restrict__ cnt) {
    int e = blockIdx.x * blockDim.x + threadIdx.x;
    if (e < NE) atomicAdd(&cnt[dst[e]], 1);
}

__global__ void k_dinv(const int* __restrict__ cnt, float* __restrict__ dinv) {
    int i = blockIdx.x * blockDim.x + threadIdx.x;
    if (i < NN) dinv[i] = rsqrtf((float)(cnt[i] + 1));  // +1 self-loop
}

__global__ __launch_bounds__(1024) void k_scan(const int* __restrict__ cnt,
                                               int* __restrict__ row_off) {
    __shared__ int part[1024];
    const int t = threadIdx.x;
    const int CH = (NN + 1023) / 1024;  // 49
    int base = t * CH;
    int s = 0;
    for (int i = base; i < base + CH && i < NN; ++i) s += cnt[i];
    part[t] = s;
    __syncthreads();
    for (int off = 1; off < 1024; off <<= 1) {
        int v = (t >= off) ? part[t - off] : 0;
        __syncthreads();
        part[t] += v;
        __syncthreads();
    }
    int run = (t == 0) ? 0 : part[t - 1];
    for (int i = base; i < base + CH && i < NN; ++i) {
        row_off[i] = run;
        run += cnt[i];
    }
    if (t == 1023) row_off[NN] = part[1023];
}

__global__ void k_fill(const int* __restrict__ src, const int* __restrict__ dst,
                       const int* __restrict__ row_off, int* __restrict__ cursor,
                       int* __restrict__ csr) {
    int e = blockIdx.x * blockDim.x + threadIdx.x;
    if (e < NE) {
        int d = dst[e];
        int pos = atomicAdd(&cursor[d], 1);
        csr[row_off[d] + pos] = src[e];
    }
}

// ---------------- conversions ----------------

// x [NN x 256] f32 -> xp [NN x 512] bf16: cols 0..255 = hi, 256..511 = lo
__global__ __launch_bounds__(256) void k_conv_x(const float* __restrict__ x,
                                                ushort* __restrict__ xp) {
    const int wid = threadIdx.x >> 6, lane = threadIdx.x & 63;
    const int row = blockIdx.x * 4 + wid;
    if (row >= NN) return;
    float4 v = *(const float4*)&x[(size_t)row * 256 + lane * 4];
    ushort4 hi, lo;
    hi.x = f2bf(v.x); lo.x = f2bf(v.x - bf2f(hi.x));
    hi.y = f2bf(v.y); lo.y = f2bf(v.y - bf2f(hi.y));
    hi.z = f2bf(v.z); lo.z = f2bf(v.z - bf2f(hi.z));
    hi.w = f2bf(v.w); lo.w = f2bf(v.w - bf2f(hi.w));
    *(ushort4*)&xp[(size_t)row * 512 + lane * 4] = hi;
    *(ushort4*)&xp[(size_t)row * 512 + 256 + lane * 4] = lo;
}

// W [KIN x NOUT] f32 -> BT [NOUT x 3*KIN] bf16: [B_hi; B_hi; B_lo] transposed
template <int KIN, int NOUT>
__global__ __launch_bounds__(256) void k_conv_w(const float* __restrict__ W,
                                                ushort* __restrict__ BT) {
    int idx = blockIdx.x * 256 + threadIdx.x;
    if (idx >= KIN * NOUT) return;
    int k = idx / NOUT, n = idx % NOUT;
    float w = W[idx];
    ushort hi = f2bf(w);
    ushort lo = f2bf(w - bf2f(hi));
    ushort* r = BT + (size_t)n * (3 * KIN);
    r[k] = hi;
    r[KIN + k] = hi;
    r[2 * KIN + k] = lo;
}

// ---------------- bf16x3 MFMA GEMM ----------------
// C16[M x N] (fp16) = (A' @ B') * dinv[row],  A' = [A_hi|A_lo] (AK=512 bf16,
// hi-block reused for k>=512), B'T = [NOUT x 768] bf16 = [B_hi;B_hi;B_lo]^T.
// 16x16x32 bf16 MFMA, global_load_lds staging, XOR-swizzled 16B slots.

template <int BM, int BN, int N>
__global__ __launch_bounds__((BM / 64) * (BN / 64) * 64) void k_gemm(
    const ushort* __restrict__ A, const ushort* __restrict__ BT,
    const float* __restrict__ dinv, ushort* __restrict__ C) {
    constexpr int WGN = BN / 64, NW = (BM / 64) * WGN;
    constexpr int K3 = 768, AK = 512, BK = 32;
    __shared__ ushort sA[BM * BK];
    __shared__ ushort sB[BN * BK];
    const int t = threadIdx.x, lane = t & 63, wid = t >> 6;
    const int wm = (wid / WGN) * 64, wn = (wid % WGN) * 64;
    constexpr int NTILES = N / BN;
    const int bm = (int)(blockIdx.x / NTILES) * BM;
    const int bn = (int)(blockIdx.x % NTILES) * BN;

    f32x4 zero = {0.f, 0.f, 0.f, 0.f};
    f32x4 acc[4][4];
#pragma unroll
    for (int m = 0; m < 4; ++m)
#pragma unroll
        for (int n = 0; n < 4; ++n) acc[m][n] = zero;

    constexpr int A_ISS = (BM * BK * 2) / (NW * 1024);
    constexpr int B_ISS = (BN * BK * 2) / (NW * 1024);

    for (int kt = 0; kt < K3; kt += BK) {
        const int akt = (kt >= AK) ? kt - AK : kt;  // A hi-block reuse for 3rd third
        __syncthreads();
#pragma unroll
        for (int i = 0; i < A_ISS; ++i) {
            int off = (wid + i * NW) << 10;
            int la = off + lane * 16;
            int row = la >> 6;
            int slot = (la >> 4) & 3;
            int scol = (slot ^ (row & 3)) << 4;
            int grow = bm + row;
            if (grow > NN - 1) grow = NN - 1;
            const char* ga = (const char*)A + (size_t)grow * (AK * 2) + akt * 2 + scol;
            __builtin_amdgcn_global_load_lds(
                (__attribute__((address_space(1))) const void*)ga,
                (__attribute__((address_space(3))) void*)((char*)sA + off), 16, 0, 0);
        }
#pragma unroll
        for (int i = 0; i < B_ISS; ++i) {
            int off = (wid + i * NW) << 10;
            int la = off + lane * 16;
            int row = la >> 6;
            int slot = (la >> 4) & 3;
            int scol = (slot ^ (row & 3)) << 4;
            const char* ga = (const char*)BT + (size_t)(bn + row) * (K3 * 2) + kt * 2 + scol;
            __builtin_amdgcn_global_load_lds(
                (__attribute__((address_space(1))) const void*)ga,
                (__attribute__((address_space(3))) void*)((char*)sB + off), 16, 0, 0);
        }
        __syncthreads();

        const int s = lane >> 4;
        const int r0 = lane & 15;
        short8 af[4], bf[4];
#pragma unroll
        for (int m = 0; m < 4; ++m) {
            int row = wm + m * 16 + r0;
            af[m] = *(const short8*)((const char*)sA + row * 64 + ((s ^ (row & 3)) << 4));
        }
#pragma unroll
        for (int n = 0; n < 4; ++n) {
            int row = wn + n * 16 + r0;
            bf[n] = *(const short8*)((const char*)sB + row * 64 + ((s ^ (row & 3)) << 4));
        }
#pragma unroll
        for (int m = 0; m < 4; ++m)
#pragma unroll
            for (int n = 0; n < 4; ++n)
                acc[m][n] = __builtin_amdgcn_mfma_f32_16x16x32_bf16(af[m], bf[n],
                                                                    acc[m][n], 0, 0, 0);
    }

    const int cr0 = (lane >> 4) * 4;
    const int cc = lane & 15;
#pragma unroll
    for (int m = 0; m < 4; ++m) {
#pragma unroll
        for (int r = 0; r < 4; ++r) {
            int row = bm + wm + m * 16 + cr0 + r;
            if (row < NN) {
                float dv = dinv[row];
#pragma unroll
                for (int n = 0; n < 4; ++n)
                    C[(size_t)row * N + bn + wn + n * 16 + cc] = f2h(acc[m][n][r] * dv);
            }
        }
    }
}

// ---------------- aggregation ----------------

// layer 1: gather 256-d fp16, accumulate fp32, relu, write bf16 hi|lo [NN x 512]
__global__ __launch_bounds__(256) void k_agg1(const ushort* __restrict__ hs,
                                              const int* __restrict__ row_off,
                                              const int* __restrict__ csr,
                                              const float* __restrict__ dinv,
                                              const float* __restrict__ bias,
                                              ushort* __restrict__ hp) {
    const int wid = threadIdx.x >> 6;
    const int lane = threadIdx.x & 63;
    const int node = blockIdx.x * 4 + wid;
    if (node >= NN) return;

    float acc[4];
    {
        ushort4 v = *(const ushort4*)&hs[(size_t)node * 256 + lane * 4];
        acc[0] = h2f(v.x); acc[1] = h2f(v.y); acc[2] = h2f(v.z); acc[3] = h2f(v.w);
    }
    const int s0 = row_off[node], s1 = row_off[node + 1];
    for (int j = s0; j < s1; ++j) {
        int s = csr[j];
        ushort4 v = *(const ushort4*)&hs[(size_t)s * 256 + lane * 4];
        acc[0] += h2f(v.x); acc[1] += h2f(v.y); acc[2] += h2f(v.z); acc[3] += h2f(v.w);
    }
    const float di = dinv[node];
    ushort4 hi, lo;
    float r0 = fmaxf(di * acc[0] + bias[lane * 4 + 0], 0.f);
    float r1 = fmaxf(di * acc[1] + bias[lane * 4 + 1], 0.f);
    float r2 = fmaxf(di * acc[2] + bias[lane * 4 + 2], 0.f);
    float r3 = fmaxf(di * acc[3] + bias[lane * 4 + 3], 0.f);
    hi.x = f2bf(r0); lo.x = f2bf(r0 - bf2f(hi.x));
    hi.y = f2bf(r1); lo.y = f2bf(r1 - bf2f(hi.y));
    hi.z = f2bf(r2); lo.z = f2bf(r2 - bf2f(hi.z));
    hi.w = f2bf(r3); lo.w = f2bf(r3 - bf2f(hi.w));
    *(ushort4*)&hp[(size_t)node * 512 + lane * 4] = hi;
    *(ushort4*)&hp[(size_t)node * 512 + 256 + lane * 4] = lo;
}

// layer 2: gather 128-d fp16, accumulate fp32, +bias, write fp32 feats (stride 384)
__global__ __launch_bounds__(256) void k_agg2(const ushort* __restrict__ hs,
                                              const int* __restrict__ row_off,
                                              const int* __restrict__ csr,
                                              const float* __restrict__ dinv,
                                              const float* __restrict__ bias,
                                              float* __restrict__ out) {
    const int wid = threadIdx.x >> 6;
    const int lane = threadIdx.x & 63;
    const int node = blockIdx.x * 4 + wid;
    if (node >= NN) return;

    float a0, a1;
    {
        ushort2 v = *(const ushort2*)&hs[(size_t)node * 128 + lane * 2];
        a0 = h2f(v.x); a1 = h2f(v.y);
    }
    const int s0 = row_off[node], s1 = row_off[node + 1];
    for (int j = s0; j < s1; ++j) {
        int s = csr[j];
        ushort2 v = *(const ushort2*)&hs[(size_t)s * 128 + lane * 2];
        a0 += h2f(v.x); a1 += h2f(v.y);
    }
    const float di = dinv[node];
    float2 o;
    o.x = di * a0 + bias[lane * 2 + 0];
    o.y = di * a1 + bias[lane * 2 + 1];
    *(float2*)&out[(size_t)node * 384 + lane * 2] = o;
}

// ---------------- attention fusion ----------------

__global__ __launch_bounds__(256) void k_attn(const float* __restrict__ feats,
                                              const float* __restrict__ attn_w,
                                              const float* __restrict__ attn_b,
                                              float* __restrict__ out) {
    const int wid = threadIdx.x >> 6;
    const int lane = threadIdx.x & 63;
    const int node = blockIdx.x * 4 + wid;
    if (node >= NN) return;

    float2 w = *(const float2*)&attn_w[lane * 2];
    const float* f = feats + (size_t)node * 384;
    float2 f0 = *(const float2*)&f[0 * 128 + lane * 2];
    float2 f1 = *(const float2*)&f[1 * 128 + lane * 2];
    float2 f2 = *(const float2*)&f[2 * 128 + lane * 2];

    float s0 = f0.x * w.x + f0.y * w.y;
    float s1 = f1.x * w.x + f1.y * w.y;
    float s2 = f2.x * w.x + f2.y * w.y;
#pragma unroll
    for (int m = 32; m >= 1; m >>= 1) {
        s0 += __shfl_xor(s0, m);
        s1 += __shfl_xor(s1, m);
        s2 += __shfl_xor(s2, m);
    }
    float bb = attn_b[0];
    s0 += bb; s1 += bb; s2 += bb;
    float mx = fmaxf(s0, fmaxf(s1, s2));
    float e0 = expf(s0 - mx), e1 = expf(s1 - mx), e2 = expf(s2 - mx);
    float inv = 1.f / (e0 + e1 + e2);
    e0 *= inv; e1 *= inv; e2 *= inv;

    float2 o;
    o.x = f0.x * e0 + f1.x * e1 + f2.x * e2;
    o.y = f0.y * e0 + f1.y * e1 + f2.y * e2;
    *(float2*)&out[(size_t)node * 128 + lane * 2] = o;
}

// ---------------- launch ----------------

extern "C" void kernel_launch(void* const* d_in, const int* in_sizes, int n_in,
                              void* d_out, int out_size, void* d_ws, size_t ws_size,
                              hipStream_t stream) {
    const float* x = (const float*)d_in[0];
    const int* edge[3] = {(const int*)d_in[1], (const int*)d_in[2], (const int*)d_in[3]};
    const float* attn_w = (const float*)d_in[16];
    const float* attn_b = (const float*)d_in[17];

    char* ws = (char*)d_ws;
    size_t off = 0;
    auto alloc = [&](size_t bytes) -> void* {
        void* p = ws + off;
        off += (bytes + 255) & ~(size_t)255;
        return p;
    };

    float* dinv   = (float*)alloc(NN * 4);
    int*   cnt    = (int*)alloc(NN * 4);
    int*   cursor = (int*)alloc(NN * 4);
    int*   rowoff = (int*)alloc((NN + 1) * 4);
    int*   csr    = (int*)alloc((size_t)NE * 4);
    ushort* xp    = (ushort*)alloc((size_t)NN * 512 * 2);  // x hi|lo bf16
    ushort* h1p   = (ushort*)alloc((size_t)NN * 512 * 2);  // h1 hi|lo bf16
    ushort* hs16  = (ushort*)alloc((size_t)NN * 256 * 2);  // gemm out fp16 (also hs2)
    float* feats  = (float*)alloc((size_t)NN * 384 * 4);   // [N,3,128]
    ushort* BT1[3], *BT2[3];
    for (int k = 0; k < 3; ++k) {
        BT1[k] = (ushort*)alloc((size_t)256 * 768 * 2);
        BT2[k] = (ushort*)alloc((size_t)128 * 768 * 2);
    }

    const int EB = (NE + 255) / 256;
    const int NB = (NN + 255) / 256;
    const int WB = (NN + 3) / 4;

    k_conv_x<<<WB, 256, 0, stream>>>(x, xp);
    for (int k = 0; k < 3; ++k) {
        const float* w1 = (const float*)d_in[4 + k * 4 + 0];
        const float* w2 = (const float*)d_in[4 + k * 4 + 2];
        k_conv_w<256, 256><<<(256 * 256 + 255) / 256, 256, 0, stream>>>(w1, BT1[k]);
        k_conv_w<256, 128><<<(256 * 128 + 255) / 256, 256, 0, stream>>>(w2, BT2[k]);
    }

    for (int k = 0; k < 3; ++k) {
        const int* esrc = edge[k];
        const int* edst = edge[k] + NE;
        const float* b1 = (const float*)d_in[4 + k * 4 + 1];
        const float* b2 = (const float*)d_in[4 + k * 4 + 3];

        hipMemsetAsync(cnt, 0, NN * 4, stream);
        hipMemsetAsync(cursor, 0, NN * 4, stream);
        k_count<<<EB, 256, 0, stream>>>(edst, cnt);
        k_dinv<<<NB, 256, 0, stream>>>(cnt, dinv);
        k_scan<<<1, 1024, 0, stream>>>(cnt, rowoff);
        k_fill<<<EB, 256, 0, stream>>>(esrc, edst, rowoff, cursor, csr);

        // layer 1: hs = dinv*(x @ w1) via bf16x3 MFMA (fp16 out); agg -> h1 (bf16 hi|lo)
        k_gemm<128, 128, 256><<<391 * 2, 256, 0, stream>>>(xp, BT1[k], dinv, hs16);
        k_agg1<<<WB, 256, 0, stream>>>(hs16, rowoff, csr, dinv, b1, h1p);

        // layer 2: hs2 = dinv*(h1 @ w2) (fp16 out); agg -> feats[:,k,:]
        k_gemm<64, 128, 128><<<782, 128, 0, stream>>>(h1p, BT2[k], dinv, hs16);
        k_agg2<<<WB, 256, 0, stream>>>(hs16, rowoff, csr, dinv, b2, feats + k * 128);
    }

    k_attn<<<WB, 256, 0, stream>>>(feats, attn_w, attn_b, (float*)d_out);
}

// Round 4
// 857.521 us; speedup vs baseline: 1.8159x; 1.4631x over previous
//
#include <hip/hip_runtime.h>

#define NN 50000
#define NE 800000

typedef __attribute__((ext_vector_type(8))) short short8;
typedef __attribute__((ext_vector_type(4))) float f32x4;
typedef __attribute__((ext_vector_type(8))) unsigned short ushort8v;
typedef __attribute__((ext_vector_type(4))) unsigned short ushort4v;

__device__ __forceinline__ ushort f2bf(float f) {
    unsigned u = __float_as_uint(f);
    unsigned r = (u + 0x7fffu + ((u >> 16) & 1u)) >> 16;
    return (ushort)r;
}
__device__ __forceinline__ float bf2f(ushort h) {
    return __uint_as_float(((unsigned)h) << 16);
}
__device__ __forceinline__ ushort f2h(float f) {
    _Float16 h = (_Float16)f;
    return __builtin_bit_cast(ushort, h);
}
__device__ __forceinline__ float h2f(ushort u) {
    return (float)__builtin_bit_cast(_Float16, u);
}

// ---------------- CSR build (all 3 branches, 4 kernels total) ----------------

// grid = 3 * EB
__global__ __launch_bounds__(256) void k_count3(const int* __restrict__ e0,
                                                const int* __restrict__ e1,
                                                const int* __restrict__ e2,
                                                int* __restrict__ cnt3) {
    const int EB = (NE + 255) / 256;
    int b = blockIdx.x / EB;
    int e = (blockIdx.x % EB) * 256 + threadIdx.x;
    if (e >= NE) return;
    const int* dst = (b == 0 ? e0 : b == 1 ? e1 : e2) + NE;
    atomicAdd(&cnt3[b * NN + dst[e]], 1);
}

// grid = 3 * NB: seg via atomic alloc (order-free), dinv
__global__ __launch_bounds__(256) void k_alloc(const int* __restrict__ cnt3,
                                               int* __restrict__ seg3,
                                               float* __restrict__ dinv3,
                                               int* __restrict__ tot) {
    const int NB = (NN + 255) / 256;
    int b = blockIdx.x / NB;
    int i = (blockIdx.x % NB) * 256 + threadIdx.x;
    if (i >= NN) return;
    int g = b * NN + i;
    int c = cnt3[g];
    seg3[g] = atomicAdd(&tot[b], c);
    dinv3[g] = rsqrtf((float)(c + 1));
}

// grid = 3 * EB
__global__ __launch_bounds__(256) void k_fill3(const int* __restrict__ e0,
                                               const int* __restrict__ e1,
                                               const int* __restrict__ e2,
                                               const int* __restrict__ seg3,
                                               int* __restrict__ cursor3,
                                               int* __restrict__ csr3) {
    const int EB = (NE + 255) / 256;
    int b = blockIdx.x / EB;
    int e = (blockIdx.x % EB) * 256 + threadIdx.x;
    if (e >= NE) return;
    const int* ep = (b == 0 ? e0 : b == 1 ? e1 : e2);
    int s = ep[e], d = ep[NE + e];
    int g = b * NN + d;
    int pos = atomicAdd(&cursor3[g], 1);
    csr3[(size_t)b * NE + seg3[g] + pos] = s;
}

// ---------------- conversions ----------------

// x [NN x 256] f32 -> xp [NN x 512] bf16: cols 0..255 = hi, 256..511 = lo
__global__ __launch_bounds__(256) void k_conv_x(const float* __restrict__ x,
                                                ushort* __restrict__ xp) {
    const int wid = threadIdx.x >> 6, lane = threadIdx.x & 63;
    const int row = blockIdx.x * 4 + wid;
    if (row >= NN) return;
    float4 v = *(const float4*)&x[(size_t)row * 256 + lane * 4];
    ushort4 hi, lo;
    hi.x = f2bf(v.x); lo.x = f2bf(v.x - bf2f(hi.x));
    hi.y = f2bf(v.y); lo.y = f2bf(v.y - bf2f(hi.y));
    hi.z = f2bf(v.z); lo.z = f2bf(v.z - bf2f(hi.z));
    hi.w = f2bf(v.w); lo.w = f2bf(v.w - bf2f(hi.w));
    *(ushort4*)&xp[(size_t)row * 512 + lane * 4] = hi;
    *(ushort4*)&xp[(size_t)row * 512 + 256 + lane * 4] = lo;
}

// W [KIN x NOUT] f32 -> BT [NOUT x 3*KIN] bf16: [B_hi; B_hi; B_lo] transposed
template <int KIN, int NOUT>
__global__ __launch_bounds__(256) void k_conv_w(const float* __restrict__ W,
                                                ushort* __restrict__ BT) {
    int idx = blockIdx.x * 256 + threadIdx.x;
    if (idx >= KIN * NOUT) return;
    int k = idx / NOUT, n = idx % NOUT;
    float w = W[idx];
    ushort hi = f2bf(w);
    ushort lo = f2bf(w - bf2f(hi));
    ushort* r = BT + (size_t)n * (3 * KIN);
    r[k] = hi;
    r[KIN + k] = hi;
    r[2 * KIN + k] = lo;
}

// ---------------- bf16x3 MFMA GEMM ----------------

template <int BM, int BN, int N>
__global__ __launch_bounds__((BM / 64) * (BN / 64) * 64) void k_gemm(
    const ushort* __restrict__ A, const ushort* __restrict__ BT,
    const float* __restrict__ dinv, ushort* __restrict__ C) {
    constexpr int WGN = BN / 64, NW = (BM / 64) * WGN;
    constexpr int K3 = 768, AK = 512, BK = 32;
    __shared__ ushort sA[BM * BK];
    __shared__ ushort sB[BN * BK];
    const int t = threadIdx.x, lane = t & 63, wid = t >> 6;
    const int wm = (wid / WGN) * 64, wn = (wid % WGN) * 64;
    constexpr int NTILES = N / BN;
    const int bm = (int)(blockIdx.x / NTILES) * BM;
    const int bn = (int)(blockIdx.x % NTILES) * BN;

    f32x4 zero = {0.f, 0.f, 0.f, 0.f};
    f32x4 acc[4][4];
#pragma unroll
    for (int m = 0; m < 4; ++m)
#pragma unroll
        for (int n = 0; n < 4; ++n) acc[m][n] = zero;

    constexpr int A_ISS = (BM * BK * 2) / (NW * 1024);
    constexpr int B_ISS = (BN * BK * 2) / (NW * 1024);

    for (int kt = 0; kt < K3; kt += BK) {
        const int akt = (kt >= AK) ? kt - AK : kt;
        __syncthreads();
#pragma unroll
        for (int i = 0; i < A_ISS; ++i) {
            int off = (wid + i * NW) << 10;
            int la = off + lane * 16;
            int row = la >> 6;
            int slot = (la >> 4) & 3;
            int scol = (slot ^ (row & 3)) << 4;
            int grow = bm + row;
            if (grow > NN - 1) grow = NN - 1;
            const char* ga = (const char*)A + (size_t)grow * (AK * 2) + akt * 2 + scol;
            __builtin_amdgcn_global_load_lds(
                (__attribute__((address_space(1))) const void*)ga,
                (__attribute__((address_space(3))) void*)((char*)sA + off), 16, 0, 0);
        }
#pragma unroll
        for (int i = 0; i < B_ISS; ++i) {
            int off = (wid + i * NW) << 10;
            int la = off + lane * 16;
            int row = la >> 6;
            int slot = (la >> 4) & 3;
            int scol = (slot ^ (row & 3)) << 4;
            const char* ga = (const char*)BT + (size_t)(bn + row) * (K3 * 2) + kt * 2 + scol;
            __builtin_amdgcn_global_load_lds(
                (__attribute__((address_space(1))) const void*)ga,
                (__attribute__((address_space(3))) void*)((char*)sB + off), 16, 0, 0);
        }
        __syncthreads();

        const int s = lane >> 4;
        const int r0 = lane & 15;
        short8 af[4], bf[4];
#pragma unroll
        for (int m = 0; m < 4; ++m) {
            int row = wm + m * 16 + r0;
            af[m] = *(const short8*)((const char*)sA + row * 64 + ((s ^ (row & 3)) << 4));
        }
#pragma unroll
        for (int n = 0; n < 4; ++n) {
            int row = wn + n * 16 + r0;
            bf[n] = *(const short8*)((const char*)sB + row * 64 + ((s ^ (row & 3)) << 4));
        }
#pragma unroll
        for (int m = 0; m < 4; ++m)
#pragma unroll
            for (int n = 0; n < 4; ++n)
                acc[m][n] = __builtin_amdgcn_mfma_f32_16x16x32_bf16(af[m], bf[n],
                                                                    acc[m][n], 0, 0, 0);
    }

    const int cr0 = (lane >> 4) * 4;
    const int cc = lane & 15;
#pragma unroll
    for (int m = 0; m < 4; ++m) {
#pragma unroll
        for (int r = 0; r < 4; ++r) {
            int row = bm + wm + m * 16 + cr0 + r;
            if (row < NN) {
                float dv = dinv[row];
#pragma unroll
                for (int n = 0; n < 4; ++n)
                    C[(size_t)row * N + bn + wn + n * 16 + cc] = f2h(acc[m][n][r] * dv);
            }
        }
    }
}

// ---------------- aggregation ----------------
// Virtual neighbor list of length cnt+1 (item 0 = self). Half-wave owns
// alternating items; 4 independent row-loads in flight per wave.

// layer 1: gather 256-d fp16, fp32 acc, relu, write bf16 hi|lo [NN x 512]
__global__ __launch_bounds__(256) void k_agg1(const ushort* __restrict__ hs,
                                              const int* __restrict__ seg,
                                              const int* __restrict__ cnt,
                                              const int* __restrict__ csr,
                                              const float* __restrict__ dinv,
                                              const float* __restrict__ bias,
                                              ushort* __restrict__ hp) {
    const int wid = threadIdx.x >> 6;
    const int lane = threadIdx.x & 63;
    const int node = blockIdx.x * 4 + wid;
    if (node >= NN) return;
    const int half = lane >> 5, l32 = lane & 31;
    const int start = seg[node];
    const int len = cnt[node] + 1;
    const size_t colb = (size_t)l32 * 8;

    float acc[8] = {0.f, 0.f, 0.f, 0.f, 0.f, 0.f, 0.f, 0.f};
    int i = half;
    for (; i + 2 < len; i += 4) {
        int sA = (i == 0) ? node : csr[start + i - 1];
        int sB = csr[start + i + 1];
        ushort8v vA = *(const ushort8v*)&hs[(size_t)sA * 256 + colb];
        ushort8v vB = *(const ushort8v*)&hs[(size_t)sB * 256 + colb];
#pragma unroll
        for (int j = 0; j < 8; ++j) acc[j] += h2f(vA[j]);
#pragma unroll
        for (int j = 0; j < 8; ++j) acc[j] += h2f(vB[j]);
    }
    for (; i < len; i += 2) {
        int s = (i == 0) ? node : csr[start + i - 1];
        ushort8v v = *(const ushort8v*)&hs[(size_t)s * 256 + colb];
#pragma unroll
        for (int j = 0; j < 8; ++j) acc[j] += h2f(v[j]);
    }
#pragma unroll
    for (int j = 0; j < 8; ++j) acc[j] += __shfl_xor(acc[j], 32);

    const float di = dinv[node];
    ushort8v outv;
    if (half == 0) {
#pragma unroll
        for (int j = 0; j < 8; ++j) {
            float r = fmaxf(di * acc[j] + bias[l32 * 8 + j], 0.f);
            outv[j] = f2bf(r);
        }
        *(ushort8v*)&hp[(size_t)node * 512 + colb] = outv;
    } else {
#pragma unroll
        for (int j = 0; j < 8; ++j) {
            float r = fmaxf(di * acc[j] + bias[l32 * 8 + j], 0.f);
            ushort hi = f2bf(r);
            outv[j] = f2bf(r - bf2f(hi));
        }
        *(ushort8v*)&hp[(size_t)node * 512 + 256 + colb] = outv;
    }
}

// layer 2: gather 128-d fp16, fp32 acc, +bias, write fp32 feats (stride 384)
__global__ __launch_bounds__(256) void k_agg2(const ushort* __restrict__ hs,
                                              const int* __restrict__ seg,
                                              const int* __restrict__ cnt,
                                              const int* __restrict__ csr,
                                              const float* __restrict__ dinv,
                                              const float* __restrict__ bias,
                                              float* __restrict__ out) {
    const int wid = threadIdx.x >> 6;
    const int lane = threadIdx.x & 63;
    const int node = blockIdx.x * 4 + wid;
    if (node >= NN) return;
    const int half = lane >> 5, l32 = lane & 31;
    const int start = seg[node];
    const int len = cnt[node] + 1;
    const size_t colb = (size_t)l32 * 4;

    float acc[4] = {0.f, 0.f, 0.f, 0.f};
    int i = half;
    for (; i + 2 < len; i += 4) {
        int sA = (i == 0) ? node : csr[start + i - 1];
        int sB = csr[start + i + 1];
        ushort4v vA = *(const ushort4v*)&hs[(size_t)sA * 128 + colb];
        ushort4v vB = *(const ushort4v*)&hs[(size_t)sB * 128 + colb];
#pragma unroll
        for (int j = 0; j < 4; ++j) acc[j] += h2f(vA[j]);
#pragma unroll
        for (int j = 0; j < 4; ++j) acc[j] += h2f(vB[j]);
    }
    for (; i < len; i += 2) {
        int s = (i == 0) ? node : csr[start + i - 1];
        ushort4v v = *(const ushort4v*)&hs[(size_t)s * 128 + colb];
#pragma unroll
        for (int j = 0; j < 4; ++j) acc[j] += h2f(v[j]);
    }
#pragma unroll
    for (int j = 0; j < 4; ++j) acc[j] += __shfl_xor(acc[j], 32);

    if (half == 0) {
        const float di = dinv[node];
        float4 o;
        o.x = di * acc[0] + bias[l32 * 4 + 0];
        o.y = di * acc[1] + bias[l32 * 4 + 1];
        o.z = di * acc[2] + bias[l32 * 4 + 2];
        o.w = di * acc[3] + bias[l32 * 4 + 3];
        *(float4*)&out[(size_t)node * 384 + colb] = o;
    }
}

// ---------------- attention fusion ----------------

__global__ __launch_bounds__(256) void k_attn(const float* __restrict__ feats,
                                              const float* __restrict__ attn_w,
                                              const float* __restrict__ attn_b,
                                              float* __restrict__ out) {
    const int wid = threadIdx.x >> 6;
    const int lane = threadIdx.x & 63;
    const int node = blockIdx.x * 4 + wid;
    if (node >= NN) return;

    float2 w = *(const float2*)&attn_w[lane * 2];
    const float* f = feats + (size_t)node * 384;
    float2 f0 = *(const float2*)&f[0 * 128 + lane * 2];
    float2 f1 = *(const float2*)&f[1 * 128 + lane * 2];
    float2 f2 = *(const float2*)&f[2 * 128 + lane * 2];

    float s0 = f0.x * w.x + f0.y * w.y;
    float s1 = f1.x * w.x + f1.y * w.y;
    float s2 = f2.x * w.x + f2.y * w.y;
#pragma unroll
    for (int m = 32; m >= 1; m >>= 1) {
        s0 += __shfl_xor(s0, m);
        s1 += __shfl_xor(s1, m);
        s2 += __shfl_xor(s2, m);
    }
    float bb = attn_b[0];
    s0 += bb; s1 += bb; s2 += bb;
    float mx = fmaxf(s0, fmaxf(s1, s2));
    float e0 = expf(s0 - mx), e1 = expf(s1 - mx), e2 = expf(s2 - mx);
    float inv = 1.f / (e0 + e1 + e2);
    e0 *= inv; e1 *= inv; e2 *= inv;

    float2 o;
    o.x = f0.x * e0 + f1.x * e1 + f2.x * e2;
    o.y = f0.y * e0 + f1.y * e1 + f2.y * e2;
    *(float2*)&out[(size_t)node * 128 + lane * 2] = o;
}

// ---------------- launch ----------------

extern "C" void kernel_launch(void* const* d_in, const int* in_sizes, int n_in,
                              void* d_out, int out_size, void* d_ws, size_t ws_size,
                              hipStream_t stream) {
    const float* x = (const float*)d_in[0];
    const int* e0 = (const int*)d_in[1];
    const int* e1 = (const int*)d_in[2];
    const int* e2 = (const int*)d_in[3];
    const float* attn_w = (const float*)d_in[16];
    const float* attn_b = (const float*)d_in[17];

    char* ws = (char*)d_ws;
    size_t off = 0;
    auto alloc = [&](size_t bytes) -> void* {
        void* p = ws + off;
        off += (bytes + 255) & ~(size_t)255;
        return p;
    };

    // contiguous zero-region: cnt3 | cursor3 | tot
    int* cnt3    = (int*)alloc((size_t)3 * NN * 4);   // 2.4MB (256B-multiple)
    int* cursor3 = (int*)alloc((size_t)3 * NN * 4);
    int* tot     = (int*)alloc(256 * 4);
    size_t zero_bytes = (size_t)3 * NN * 4 * 2 + 256 * 4;

    int*   seg3  = (int*)alloc((size_t)3 * NN * 4);
    float* dinv3 = (float*)alloc((size_t)3 * NN * 4);
    int*   csr3  = (int*)alloc((size_t)3 * NE * 4);
    ushort* xp   = (ushort*)alloc((size_t)NN * 512 * 2);
    ushort* h1p  = (ushort*)alloc((size_t)NN * 512 * 2);
    ushort* hs16 = (ushort*)alloc((size_t)NN * 256 * 2);
    float* feats = (float*)alloc((size_t)NN * 384 * 4);
    ushort* BT1[3], *BT2[3];
    for (int k = 0; k < 3; ++k) {
        BT1[k] = (ushort*)alloc((size_t)256 * 768 * 2);
        BT2[k] = (ushort*)alloc((size_t)128 * 768 * 2);
    }

    const int EB = (NE + 255) / 256;
    const int NB = (NN + 255) / 256;
    const int WB = (NN + 3) / 4;

    hipMemsetAsync(cnt3, 0, zero_bytes, stream);
    k_conv_x<<<WB, 256, 0, stream>>>(x, xp);
    for (int k = 0; k < 3; ++k) {
        const float* w1 = (const float*)d_in[4 + k * 4 + 0];
        const float* w2 = (const float*)d_in[4 + k * 4 + 2];
        k_conv_w<256, 256><<<(256 * 256 + 255) / 256, 256, 0, stream>>>(w1, BT1[k]);
        k_conv_w<256, 128><<<(256 * 128 + 255) / 256, 256, 0, stream>>>(w2, BT2[k]);
    }
    k_count3<<<3 * EB, 256, 0, stream>>>(e0, e1, e2, cnt3);
    k_alloc<<<3 * NB, 256, 0, stream>>>(cnt3, seg3, dinv3, tot);
    k_fill3<<<3 * EB, 256, 0, stream>>>(e0, e1, e2, seg3, cursor3, csr3);

    for (int k = 0; k < 3; ++k) {
        const float* b1 = (const float*)d_in[4 + k * 4 + 1];
        const float* b2 = (const float*)d_in[4 + k * 4 + 3];
        const int* seg = seg3 + (size_t)k * NN;
        const int* cnt = cnt3 + (size_t)k * NN;
        const int* csr = csr3 + (size_t)k * NE;
        const float* dinv = dinv3 + (size_t)k * NN;

        k_gemm<128, 128, 256><<<391 * 2, 256, 0, stream>>>(xp, BT1[k], dinv, hs16);
        k_agg1<<<WB, 256, 0, stream>>>(hs16, seg, cnt, csr, dinv, b1, h1p);

        k_gemm<64, 128, 128><<<782, 128, 0, stream>>>(h1p, BT2[k], dinv, hs16);
        k_agg2<<<WB, 256, 0, stream>>>(hs16, seg, cnt, csr, dinv, b2, feats + k * 128);
    }

    k_attn<<<WB, 256, 0, stream>>>(feats, attn_w, attn_b, (float*)d_out);
}

// Round 5
// 644.991 us; speedup vs baseline: 2.4142x; 1.3295x over previous
//
#include <hip/hip_runtime.h>

#define NN 50000
#define NE 800000

typedef __attribute__((ext_vector_type(8))) short short8;
typedef __attribute__((ext_vector_type(4))) float f32x4;
typedef __attribute__((ext_vector_type(8))) unsigned short ushort8v;
typedef __attribute__((ext_vector_type(4))) unsigned short ushort4v;
typedef _Float16 half8 __attribute__((ext_vector_type(8)));

__device__ __forceinline__ ushort f2bf(float f) {
    unsigned u = __float_as_uint(f);
    unsigned r = (u + 0x7fffu + ((u >> 16) & 1u)) >> 16;
    return (ushort)r;
}
__device__ __forceinline__ float bf2f(ushort h) {
    return __uint_as_float(((unsigned)h) << 16);
}
__device__ __forceinline__ ushort f2h(float f) {
    _Float16 h = (_Float16)f;
    return __builtin_bit_cast(ushort, h);
}
__device__ __forceinline__ float h2f(ushort u) {
    return (float)__builtin_bit_cast(_Float16, u);
}

// ---------------- bucket-CSR build ----------------
// buckets[(b*NN+node)*64 + pos] = src (ushort). cursor3 = true degree after fill.

__global__ __launch_bounds__(256) void k_fillB(const int* __restrict__ e0,
                                               const int* __restrict__ e1,
                                               const int* __restrict__ e2,
                                               int* __restrict__ cursor3,
                                               ushort* __restrict__ buckets) {
    constexpr int TPB = 782;  // blocks per branch; 782*256*4 >= NE
    const int b = blockIdx.x / TPB;
    const int t = (blockIdx.x % TPB) * 256 + threadIdx.x;
    const int* ep = (b == 0 ? e0 : b == 1 ? e1 : e2);
    const int e = t * 4;
    if (e + 4 <= NE) {  // NE % 4 == 0, no partial tail
        int4 s4 = *(const int4*)&ep[e];
        int4 d4 = *(const int4*)&ep[NE + e];
        int g0 = b * NN + d4.x;
        int g1 = b * NN + d4.y;
        int g2 = b * NN + d4.z;
        int g3 = b * NN + d4.w;
        int p0 = atomicAdd(&cursor3[g0], 1);
        int p1 = atomicAdd(&cursor3[g1], 1);
        int p2 = atomicAdd(&cursor3[g2], 1);
        int p3 = atomicAdd(&cursor3[g3], 1);
        if (p0 < 64) buckets[((size_t)g0 << 6) + p0] = (ushort)s4.x;
        if (p1 < 64) buckets[((size_t)g1 << 6) + p1] = (ushort)s4.y;
        if (p2 < 64) buckets[((size_t)g2 << 6) + p2] = (ushort)s4.z;
        if (p3 < 64) buckets[((size_t)g3 << 6) + p3] = (ushort)s4.w;
    }
}

__global__ __launch_bounds__(256) void k_dinv3(const int* __restrict__ cursor3,
                                               float* __restrict__ dinv3) {
    int i = blockIdx.x * 256 + threadIdx.x;
    if (i < 3 * NN) dinv3[i] = rsqrtf((float)(cursor3[i] + 1));
}

// ---------------- conversions ----------------

// x [NN x 256] f32 -> xp [NN x 512] bf16 hi|lo
__global__ __launch_bounds__(256) void k_conv_x(const float* __restrict__ x,
                                                ushort* __restrict__ xp) {
    const int wid = threadIdx.x >> 6, lane = threadIdx.x & 63;
    const int row = blockIdx.x * 4 + wid;
    if (row >= NN) return;
    float4 v = *(const float4*)&x[(size_t)row * 256 + lane * 4];
    ushort4 hi, lo;
    hi.x = f2bf(v.x); lo.x = f2bf(v.x - bf2f(hi.x));
    hi.y = f2bf(v.y); lo.y = f2bf(v.y - bf2f(hi.y));
    hi.z = f2bf(v.z); lo.z = f2bf(v.z - bf2f(hi.z));
    hi.w = f2bf(v.w); lo.w = f2bf(v.w - bf2f(hi.w));
    *(ushort4*)&xp[(size_t)row * 512 + lane * 4] = hi;
    *(ushort4*)&xp[(size_t)row * 512 + 256 + lane * 4] = lo;
}

// W1 [256x256] f32 -> BT1 [256 x 768] bf16 = [hi;hi;lo]^T, batched over 3
__global__ __launch_bounds__(256) void k_conv_w1(const float* __restrict__ w0,
                                                 const float* __restrict__ w1,
                                                 const float* __restrict__ w2,
                                                 ushort* __restrict__ BT1all) {
    int idx = blockIdx.x * 256 + threadIdx.x;  // 3 * 65536
    int b = idx >> 16, r = idx & 65535;
    int k = r >> 8, n = r & 255;
    const float* W = (b == 0 ? w0 : b == 1 ? w1 : w2);
    float w = W[r];
    ushort hi = f2bf(w);
    ushort lo = f2bf(w - bf2f(hi));
    ushort* row = BT1all + (size_t)b * 196608 + (size_t)n * 768;
    row[k] = hi;
    row[256 + k] = hi;
    row[512 + k] = lo;
}

// W2 [256x128] f32 -> BT2 [128 x 256] fp16 (transpose), batched over 3
__global__ __launch_bounds__(256) void k_conv_w2(const float* __restrict__ w0,
                                                 const float* __restrict__ w1,
                                                 const float* __restrict__ w2,
                                                 ushort* __restrict__ BT2all) {
    int idx = blockIdx.x * 256 + threadIdx.x;  // 3 * 32768
    int b = idx >> 15, r = idx & 32767;
    int k = r >> 7, n = r & 127;
    const float* W = (b == 0 ? w0 : b == 1 ? w1 : w2);
    BT2all[(size_t)b * 32768 + (size_t)n * 256 + k] = f2h(W[r]);
}

// ---------------- MFMA GEMM (bf16x3 or fp16), batched over 3 branches ----------------
// C16[M x N] = (A @ BT^T) * dinv[row]; A rows are AK elems (bf16/f16), BT rows KK.
// For KK>AK (bf16x3): k>=AK reuses A cols k-AK (hi-block) -- BT carries [hi;hi;lo].

template <int BM, int BN, int N, int KK, int AK, bool HALF>
__global__ __launch_bounds__((BM / 64) * (BN / 64) * 64) void k_gemm(
    const ushort* __restrict__ A, size_t aBatch,
    const ushort* __restrict__ BTall, int btBatch,
    const float* __restrict__ dinv3, ushort* __restrict__ Call, size_t cBatch) {
    constexpr int WGN = BN / 64, NW = (BM / 64) * WGN;
    constexpr int BK = 32;
    constexpr int MT = (NN + BM - 1) / BM, NT = N / BN, GB = MT * NT;
    __shared__ ushort sA[BM * BK];
    __shared__ ushort sB[BN * BK];
    const int kb = blockIdx.x / GB;
    const int bid = blockIdx.x % GB;
    const ushort* Ab = A + (size_t)kb * aBatch;
    const ushort* BT = BTall + (size_t)kb * btBatch;
    const float* dinv = dinv3 + (size_t)kb * NN;
    ushort* C = Call + (size_t)kb * cBatch;
    const int t = threadIdx.x, lane = t & 63, wid = t >> 6;
    const int wm = (wid / WGN) * 64, wn = (wid % WGN) * 64;
    const int bm = (bid / NT) * BM;
    const int bn = (bid % NT) * BN;

    f32x4 zero = {0.f, 0.f, 0.f, 0.f};
    f32x4 acc[4][4];
#pragma unroll
    for (int m = 0; m < 4; ++m)
#pragma unroll
        for (int n = 0; n < 4; ++n) acc[m][n] = zero;

    constexpr int A_ISS = (BM * BK * 2) / (NW * 1024);
    constexpr int B_ISS = (BN * BK * 2) / (NW * 1024);

    for (int kt = 0; kt < KK; kt += BK) {
        const int akt = (kt >= AK) ? kt - AK : kt;
        __syncthreads();
#pragma unroll
        for (int i = 0; i < A_ISS; ++i) {
            int off = (wid + i * NW) << 10;
            int la = off + lane * 16;
            int row = la >> 6;
            int slot = (la >> 4) & 3;
            int scol = (slot ^ (row & 3)) << 4;
            int grow = bm + row;
            if (grow > NN - 1) grow = NN - 1;
            const char* ga = (const char*)Ab + (size_t)grow * (AK * 2) + akt * 2 + scol;
            __builtin_amdgcn_global_load_lds(
                (__attribute__((address_space(1))) const void*)ga,
                (__attribute__((address_space(3))) void*)((char*)sA + off), 16, 0, 0);
        }
#pragma unroll
        for (int i = 0; i < B_ISS; ++i) {
            int off = (wid + i * NW) << 10;
            int la = off + lane * 16;
            int row = la >> 6;
            int slot = (la >> 4) & 3;
            int scol = (slot ^ (row & 3)) << 4;
            const char* ga = (const char*)BT + (size_t)(bn + row) * (KK * 2) + kt * 2 + scol;
            __builtin_amdgcn_global_load_lds(
                (__attribute__((address_space(1))) const void*)ga,
                (__attribute__((address_space(3))) void*)((char*)sB + off), 16, 0, 0);
        }
        __syncthreads();

        const int s = lane >> 4;
        const int r0 = lane & 15;
        short8 af[4], bf[4];
#pragma unroll
        for (int m = 0; m < 4; ++m) {
            int row = wm + m * 16 + r0;
            af[m] = *(const short8*)((const char*)sA + row * 64 + ((s ^ (row & 3)) << 4));
        }
#pragma unroll
        for (int n = 0; n < 4; ++n) {
            int row = wn + n * 16 + r0;
            bf[n] = *(const short8*)((const char*)sB + row * 64 + ((s ^ (row & 3)) << 4));
        }
#pragma unroll
        for (int m = 0; m < 4; ++m)
#pragma unroll
            for (int n = 0; n < 4; ++n) {
                if constexpr (HALF)
                    acc[m][n] = __builtin_amdgcn_mfma_f32_16x16x32_f16(
                        __builtin_bit_cast(half8, af[m]), __builtin_bit_cast(half8, bf[n]),
                        acc[m][n], 0, 0, 0);
                else
                    acc[m][n] = __builtin_amdgcn_mfma_f32_16x16x32_bf16(af[m], bf[n],
                                                                        acc[m][n], 0, 0, 0);
            }
    }

    const int cr0 = (lane >> 4) * 4;
    const int cc = lane & 15;
#pragma unroll
    for (int m = 0; m < 4; ++m) {
#pragma unroll
        for (int r = 0; r < 4; ++r) {
            int row = bm + wm + m * 16 + cr0 + r;
            if (row < NN) {
                float dv = dinv[row];
#pragma unroll
                for (int n = 0; n < 4; ++n)
                    C[(size_t)row * N + bn + wn + n * 16 + cc] = f2h(acc[m][n][r] * dv);
            }
        }
    }
}

// ---------------- layer-1 aggregation (batched over 3 branches) ----------------
// Virtual list: item 0 = self, item m = csr[m-1]. Half-wave owns alternating
// items, 4-deep unroll -> 8 row loads in flight per wave. Output plain fp16.

__global__ __launch_bounds__(256) void k_agg1(const ushort* __restrict__ hs16all,
                                              const int* __restrict__ cursor3,
                                              const ushort* __restrict__ buckets,
                                              const float* __restrict__ dinv3,
                                              const float* __restrict__ b1a,
                                              const float* __restrict__ b1b,
                                              const float* __restrict__ b1c,
                                              ushort* __restrict__ h1all) {
    constexpr int WBn = (NN + 3) / 4;
    const int b = blockIdx.x / WBn;
    const int blk = blockIdx.x % WBn;
    const int wid = threadIdx.x >> 6;
    const int lane = threadIdx.x & 63;
    const int node = blk * 4 + wid;
    if (node >= NN) return;
    const int half = lane >> 5, l32 = lane & 31;
    const int g = b * NN + node;
    const ushort* hs = hs16all + (size_t)b * NN * 256;
    const ushort* csr = buckets + ((size_t)g << 6);
    const int len = min(cursor3[g], 64) + 1;
    const size_t colb = (size_t)l32 * 8;

    float acc[8] = {0.f, 0.f, 0.f, 0.f, 0.f, 0.f, 0.f, 0.f};
    int i = half;
    for (; i + 6 < len; i += 8) {
        int s0 = (i == 0) ? node : (int)csr[i - 1];
        int s1 = (int)csr[i + 1];
        int s2 = (int)csr[i + 3];
        int s3 = (int)csr[i + 5];
        ushort8v v0 = *(const ushort8v*)&hs[(size_t)s0 * 256 + colb];
        ushort8v v1 = *(const ushort8v*)&hs[(size_t)s1 * 256 + colb];
        ushort8v v2 = *(const ushort8v*)&hs[(size_t)s2 * 256 + colb];
        ushort8v v3 = *(const ushort8v*)&hs[(size_t)s3 * 256 + colb];
#pragma unroll
        for (int j = 0; j < 8; ++j)
            acc[j] += (h2f(v0[j]) + h2f(v1[j])) + (h2f(v2[j]) + h2f(v3[j]));
    }
    for (; i < len; i += 2) {
        int s = (i == 0) ? node : (int)csr[i - 1];
        ushort8v v = *(const ushort8v*)&hs[(size_t)s * 256 + colb];
#pragma unroll
        for (int j = 0; j < 8; ++j) acc[j] += h2f(v[j]);
    }
#pragma unroll
    for (int j = 0; j < 8; ++j) acc[j] += __shfl_xor(acc[j], 32);

    if (half == 0) {
        const float* bias = (b == 0 ? b1a : b == 1 ? b1b : b1c);
        const float di = dinv3[g];
        ushort8v o;
#pragma unroll
        for (int j = 0; j < 8; ++j) {
            float r = fmaxf(di * acc[j] + bias[l32 * 8 + j], 0.f);
            o[j] = f2h(r);
        }
        *(ushort8v*)&h1all[((size_t)b * NN + node) * 256 + colb] = o;
    }
}

// ---------------- fused layer-2 aggregation (x3) + attention ----------------

__global__ __launch_bounds__(256) void k_final(const ushort* __restrict__ hs2all,
                                               const int* __restrict__ cursor3,
                                               const ushort* __restrict__ buckets,
                                               const float* __restrict__ dinv3,
                                               const float* __restrict__ b2a,
                                               const float* __restrict__ b2b,
                                               const float* __restrict__ b2c,
                                               const float* __restrict__ attn_w,
                                               const float* __restrict__ attn_b,
                                               float* __restrict__ out) {
    const int wid = threadIdx.x >> 6;
    const int lane = threadIdx.x & 63;
    const int node = blockIdx.x * 4 + wid;
    if (node >= NN) return;
    const int half = lane >> 5, l32 = lane & 31;
    const size_t colb = (size_t)l32 * 4;

    float f[3][4];
#pragma unroll
    for (int b = 0; b < 3; ++b) {
        const int g = b * NN + node;
        const ushort* hs = hs2all + (size_t)b * NN * 128;
        const ushort* csr = buckets + ((size_t)g << 6);
        const int len = min(cursor3[g], 64) + 1;
        float acc[4] = {0.f, 0.f, 0.f, 0.f};
        int i = half;
        for (; i + 6 < len; i += 8) {
            int s0 = (i == 0) ? node : (int)csr[i - 1];
            int s1 = (int)csr[i + 1];
            int s2 = (int)csr[i + 3];
            int s3 = (int)csr[i + 5];
            ushort4v v0 = *(const ushort4v*)&hs[(size_t)s0 * 128 + colb];
            ushort4v v1 = *(const ushort4v*)&hs[(size_t)s1 * 128 + colb];
            ushort4v v2 = *(const ushort4v*)&hs[(size_t)s2 * 128 + colb];
            ushort4v v3 = *(const ushort4v*)&hs[(size_t)s3 * 128 + colb];
#pragma unroll
            for (int j = 0; j < 4; ++j)
                acc[j] += (h2f(v0[j]) + h2f(v1[j])) + (h2f(v2[j]) + h2f(v3[j]));
        }
        for (; i < len; i += 2) {
            int s = (i == 0) ? node : (int)csr[i - 1];
            ushort4v v = *(const ushort4v*)&hs[(size_t)s * 128 + colb];
#pragma unroll
            for (int j = 0; j < 4; ++j) acc[j] += h2f(v[j]);
        }
#pragma unroll
        for (int j = 0; j < 4; ++j) acc[j] += __shfl_xor(acc[j], 32);
        const float* bias = (b == 0 ? b2a : b == 1 ? b2b : b2c);
        const float di = dinv3[g];
#pragma unroll
        for (int j = 0; j < 4; ++j) f[b][j] = di * acc[j] + bias[l32 * 4 + j];
    }

    // attention over 3 branches
    float4 w = *(const float4*)&attn_w[l32 * 4];
    float s0 = f[0][0] * w.x + f[0][1] * w.y + f[0][2] * w.z + f[0][3] * w.w;
    float s1 = f[1][0] * w.x + f[1][1] * w.y + f[1][2] * w.z + f[1][3] * w.w;
    float s2 = f[2][0] * w.x + f[2][1] * w.y + f[2][2] * w.z + f[2][3] * w.w;
#pragma unroll
    for (int m = 16; m >= 1; m >>= 1) {
        s0 += __shfl_xor(s0, m);
        s1 += __shfl_xor(s1, m);
        s2 += __shfl_xor(s2, m);
    }
    float bb = attn_b[0];
    s0 += bb; s1 += bb; s2 += bb;
    float mx = fmaxf(s0, fmaxf(s1, s2));
    float e0 = expf(s0 - mx), e1 = expf(s1 - mx), e2 = expf(s2 - mx);
    float inv = 1.f / (e0 + e1 + e2);
    e0 *= inv; e1 *= inv; e2 *= inv;

    if (half == 0) {
        float4 o;
        o.x = f[0][0] * e0 + f[1][0] * e1 + f[2][0] * e2;
        o.y = f[0][1] * e0 + f[1][1] * e1 + f[2][1] * e2;
        o.z = f[0][2] * e0 + f[1][2] * e1 + f[2][2] * e2;
        o.w = f[0][3] * e0 + f[1][3] * e1 + f[2][3] * e2;
        *(float4*)&out[(size_t)node * 128 + colb] = o;
    }
}

// ---------------- launch ----------------

extern "C" void kernel_launch(void* const* d_in, const int* in_sizes, int n_in,
                              void* d_out, int out_size, void* d_ws, size_t ws_size,
                              hipStream_t stream) {
    const float* x = (const float*)d_in[0];
    const int* e0 = (const int*)d_in[1];
    const int* e1 = (const int*)d_in[2];
    const int* e2 = (const int*)d_in[3];
    const float* attn_w = (const float*)d_in[16];
    const float* attn_b = (const float*)d_in[17];

    char* ws = (char*)d_ws;
    size_t off = 0;
    auto alloc = [&](size_t bytes) -> void* {
        void* p = ws + off;
        off += (bytes + 255) & ~(size_t)255;
        return p;
    };

    int* cursor3    = (int*)alloc((size_t)3 * NN * 4);            // 600 KB (zeroed)
    float* dinv3    = (float*)alloc((size_t)3 * NN * 4);
    ushort* buckets = (ushort*)alloc((size_t)3 * NN * 64 * 2);    // 19.2 MB
    ushort* xp      = (ushort*)alloc((size_t)NN * 512 * 2);       // 51.2 MB
    ushort* hs2all  = xp;  // alias: xp dead after gemm1, hs2 (38.4 MB) fits
    ushort* hs16all = (ushort*)alloc((size_t)3 * NN * 256 * 2);   // 76.8 MB
    ushort* h1all   = (ushort*)alloc((size_t)3 * NN * 256 * 2);   // 76.8 MB
    ushort* BT1all  = (ushort*)alloc((size_t)3 * 256 * 768 * 2);
    ushort* BT2all  = (ushort*)alloc((size_t)3 * 128 * 256 * 2);

    const int WB = (NN + 3) / 4;  // 12500

    hipMemsetAsync(cursor3, 0, (size_t)3 * NN * 4, stream);
    k_conv_x<<<WB, 256, 0, stream>>>(x, xp);
    k_conv_w1<<<768, 256, 0, stream>>>((const float*)d_in[4], (const float*)d_in[8],
                                       (const float*)d_in[12], BT1all);
    k_conv_w2<<<384, 256, 0, stream>>>((const float*)d_in[6], (const float*)d_in[10],
                                       (const float*)d_in[14], BT2all);
    k_fillB<<<3 * 782, 256, 0, stream>>>(e0, e1, e2, cursor3, buckets);
    k_dinv3<<<(3 * NN + 255) / 256, 256, 0, stream>>>(cursor3, dinv3);

    // layer 1: hs = dinv*(x @ W1) bf16x3 -> fp16, all branches
    k_gemm<128, 128, 256, 768, 512, false><<<3 * 391 * 2, 256, 0, stream>>>(
        xp, 0, BT1all, 196608, dinv3, hs16all, (size_t)NN * 256);
    k_agg1<<<3 * WB, 256, 0, stream>>>(hs16all, cursor3, buckets, dinv3,
                                       (const float*)d_in[5], (const float*)d_in[9],
                                       (const float*)d_in[13], h1all);

    // layer 2: hs2 = dinv*(h1 @ W2) fp16, all branches
    k_gemm<128, 128, 128, 256, 256, true><<<3 * 391, 256, 0, stream>>>(
        h1all, (size_t)NN * 256, BT2all, 32768, dinv3, hs2all, (size_t)NN * 128);

    // fused layer-2 aggregation + attention
    k_final<<<WB, 256, 0, stream>>>(hs2all, cursor3, buckets, dinv3,
                                    (const float*)d_in[7], (const float*)d_in[11],
                                    (const float*)d_in[15], attn_w, attn_b,
                                    (float*)d_out);
}

// Round 6
// 498.170 us; speedup vs baseline: 3.1257x; 1.2947x over previous
//
#include <hip/hip_runtime.h>

#define NN 50000
#define NE 800000
#define BINS 98      // bins of 512 nodes per branch
#define CAP 12288    // per-bin capacity (u32 records / ushort csr entries)
#define EPB 4096     // edges per phase-1 block
#define P1B ((NE + EPB - 1) / EPB)  // 196 blocks per branch

typedef __attribute__((ext_vector_type(8))) short short8;
typedef __attribute__((ext_vector_type(4))) float f32x4;
typedef __attribute__((ext_vector_type(8))) unsigned short ushort8v;
typedef __attribute__((ext_vector_type(4))) unsigned short ushort4v;
typedef _Float16 half8 __attribute__((ext_vector_type(8)));

__device__ __forceinline__ ushort f2bf(float f) {
    unsigned u = __float_as_uint(f);
    unsigned r = (u + 0x7fffu + ((u >> 16) & 1u)) >> 16;
    return (ushort)r;
}
__device__ __forceinline__ float bf2f(ushort h) {
    return __uint_as_float(((unsigned)h) << 16);
}
__device__ __forceinline__ ushort f2h(float f) {
    _Float16 h = (_Float16)f;
    return __builtin_bit_cast(ushort, h);
}
__device__ __forceinline__ float h2f(ushort u) {
    return (float)__builtin_bit_cast(_Float16, u);
}

// ---------------- phase 1: bin edges by dst>>9, coalesced line-exclusive flush ----

__global__ __launch_bounds__(256) void k_bin(const int* __restrict__ e0,
                                             const int* __restrict__ e1,
                                             const int* __restrict__ e2,
                                             int* __restrict__ g_cur,
                                             unsigned* __restrict__ g_bins) {
    const int br = blockIdx.x / P1B;
    const int cb = blockIdx.x % P1B;
    const int* ep = (br == 0 ? e0 : br == 1 ? e1 : e2);
    const int tid = threadIdx.x;
    const int e_base = cb * EPB;

    __shared__ int s_cnt[BINS];
    __shared__ int s_start[BINS];
    __shared__ int s_cur[BINS];
    __shared__ int s_gb[BINS];
    __shared__ unsigned s_stage[EPB];

    if (tid < BINS) s_cnt[tid] = 0;
    __syncthreads();

    int4 s4[4], d4[4];
    bool valid[4];
#pragma unroll
    for (int i = 0; i < 4; ++i) {
        int idx = e_base + i * 1024 + tid * 4;
        valid[i] = (idx < NE);  // idx%4==0, NE%4==0 -> full int4 valid
        if (valid[i]) {
            s4[i] = *(const int4*)&ep[idx];
            d4[i] = *(const int4*)&ep[NE + idx];
            atomicAdd(&s_cnt[d4[i].x >> 9], 1);
            atomicAdd(&s_cnt[d4[i].y >> 9], 1);
            atomicAdd(&s_cnt[d4[i].z >> 9], 1);
            atomicAdd(&s_cnt[d4[i].w >> 9], 1);
        }
    }
    __syncthreads();
    if (tid == 0) {
        int run = 0;
        for (int b = 0; b < BINS; ++b) {
            s_start[b] = run;
            run += s_cnt[b];
        }
    }
    __syncthreads();
    if (tid < BINS) {
        s_cur[tid] = s_start[tid];
        int c = s_cnt[tid];
        int pc = (c + 15) & ~15;  // 64B-aligned reservation
        s_gb[tid] = (c > 0) ? atomicAdd(&g_cur[br * BINS + tid], pc) : 0;
    }
    __syncthreads();

#pragma unroll
    for (int i = 0; i < 4; ++i) {
        if (valid[i]) {
            int ss[4] = {s4[i].x, s4[i].y, s4[i].z, s4[i].w};
            int dd[4] = {d4[i].x, d4[i].y, d4[i].z, d4[i].w};
#pragma unroll
            for (int q = 0; q < 4; ++q) {
                int bin = dd[q] >> 9;
                int pos = atomicAdd(&s_cur[bin], 1);
                s_stage[pos] = ((unsigned)(dd[q] & 511) << 16) | (unsigned)ss[q];
            }
        }
    }
    __syncthreads();

    for (int b = 0; b < BINS; ++b) {
        int c = s_cnt[b];
        if (c == 0) continue;
        int st = s_start[b];
        int gb = s_gb[b];
        int pc = (c + 15) & ~15;
        if (gb + pc > CAP) pc = (gb < CAP) ? (CAP - gb) : 0;  // overflow guard
        size_t obase = (size_t)(br * BINS + b) * CAP + gb;
        for (int j = tid; j < pc; j += 256)
            g_bins[obase + j] = (j < c) ? s_stage[st + j] : 0x80000000u;
    }
}

// ---------------- phase 2: per-bin CSR build with LDS atomics ----------------

__device__ __forceinline__ int wave_incl_scan(int v, int lane) {
#pragma unroll
    for (int d = 1; d < 64; d <<= 1) {
        int u = __shfl_up(v, d);
        if (lane >= d) v += u;
    }
    return v;
}

__global__ __launch_bounds__(256) void k_build(const unsigned* __restrict__ g_bins,
                                               const int* __restrict__ g_cur,
                                               ushort* __restrict__ g_csr,
                                               int* __restrict__ seg3,
                                               int* __restrict__ cnt3,
                                               float* __restrict__ dinv3) {
    const int bid = blockIdx.x;  // branch*BINS + bin
    const int br = bid / BINS;
    const int b2 = bid % BINS;
    const size_t base = (size_t)bid * CAP;
    const int node0 = b2 << 9;
    const int tid = threadIdx.x;

    __shared__ int s_cnt[512];
    __shared__ int s_off[512];
    __shared__ int s_wsum[4];

    s_cnt[tid] = 0;
    s_cnt[tid + 256] = 0;
    __syncthreads();

    const int total = min(g_cur[bid], CAP);
    for (int j = tid; j < total; j += 256) {
        unsigned p = g_bins[base + j];
        if (!(p & 0x80000000u)) atomicAdd(&s_cnt[(p >> 16) & 0x1FF], 1);
    }
    __syncthreads();

    // exclusive scan of 512 counts (pairs per thread + wave scan)
    const int lane = tid & 63, w = tid >> 6;
    int c0 = s_cnt[2 * tid], c1 = s_cnt[2 * tid + 1];
    int c2 = c0 + c1;
    int incl = wave_incl_scan(c2, lane);
    if (lane == 63) s_wsum[w] = incl;
    __syncthreads();
    int wpre = 0;
    for (int i = 0; i < w; ++i) wpre += s_wsum[i];
    int ex = wpre + incl - c2;
    s_off[2 * tid] = ex;
    s_off[2 * tid + 1] = ex + c0;

#pragma unroll
    for (int q = 0; q < 2; ++q) {
        int local = 2 * tid + q;
        int node = node0 + local;
        if (node < NN) {
            int g = br * NN + node;
            int c = (q == 0) ? c0 : c1;
            seg3[g] = (int)base + s_off[local];
            cnt3[g] = c;
            dinv3[g] = rsqrtf((float)(c + 1));
        }
    }
    __syncthreads();
    // cursors
    s_cnt[2 * tid] = s_off[2 * tid];
    s_cnt[2 * tid + 1] = s_off[2 * tid + 1];
    __syncthreads();

    for (int j = tid; j < total; j += 256) {
        unsigned p = g_bins[base + j];
        if (!(p & 0x80000000u)) {
            int loc = (p >> 16) & 0x1FF;
            int pos = atomicAdd(&s_cnt[loc], 1);
            g_csr[base + pos] = (ushort)(p & 0xFFFFu);
        }
    }
}

// ---------------- conversions ----------------

__global__ __launch_bounds__(256) void k_conv_x(const float* __restrict__ x,
                                                ushort* __restrict__ xp) {
    const int wid = threadIdx.x >> 6, lane = threadIdx.x & 63;
    const int row = blockIdx.x * 4 + wid;
    if (row >= NN) return;
    float4 v = *(const float4*)&x[(size_t)row * 256 + lane * 4];
    ushort4 hi, lo;
    hi.x = f2bf(v.x); lo.x = f2bf(v.x - bf2f(hi.x));
    hi.y = f2bf(v.y); lo.y = f2bf(v.y - bf2f(hi.y));
    hi.z = f2bf(v.z); lo.z = f2bf(v.z - bf2f(hi.z));
    hi.w = f2bf(v.w); lo.w = f2bf(v.w - bf2f(hi.w));
    *(ushort4*)&xp[(size_t)row * 512 + lane * 4] = hi;
    *(ushort4*)&xp[(size_t)row * 512 + 256 + lane * 4] = lo;
}

__global__ __launch_bounds__(256) void k_conv_w1(const float* __restrict__ w0,
                                                 const float* __restrict__ w1,
                                                 const float* __restrict__ w2,
                                                 ushort* __restrict__ BT1all) {
    int idx = blockIdx.x * 256 + threadIdx.x;  // 3 * 65536
    int b = idx >> 16, r = idx & 65535;
    int k = r >> 8, n = r & 255;
    const float* W = (b == 0 ? w0 : b == 1 ? w1 : w2);
    float w = W[r];
    ushort hi = f2bf(w);
    ushort lo = f2bf(w - bf2f(hi));
    ushort* row = BT1all + (size_t)b * 196608 + (size_t)n * 768;
    row[k] = hi;
    row[256 + k] = hi;
    row[512 + k] = lo;
}

__global__ __launch_bounds__(256) void k_conv_w2(const float* __restrict__ w0,
                                                 const float* __restrict__ w1,
                                                 const float* __restrict__ w2,
                                                 ushort* __restrict__ BT2all) {
    int idx = blockIdx.x * 256 + threadIdx.x;  // 3 * 32768
    int b = idx >> 15, r = idx & 32767;
    int k = r >> 7, n = r & 127;
    const float* W = (b == 0 ? w0 : b == 1 ? w1 : w2);
    BT2all[(size_t)b * 32768 + (size_t)n * 256 + k] = f2h(W[r]);
}

// ---------------- MFMA GEMM (bf16x3 or fp16), batched over 3 branches ----------------

template <int BM, int BN, int N, int KK, int AK, bool HALF>
__global__ __launch_bounds__((BM / 64) * (BN / 64) * 64) void k_gemm(
    const ushort* __restrict__ A, size_t aBatch,
    const ushort* __restrict__ BTall, int btBatch,
    const float* __restrict__ dinv3, ushort* __restrict__ Call, size_t cBatch) {
    constexpr int WGN = BN / 64, NW = (BM / 64) * WGN;
    constexpr int BK = 32;
    constexpr int MT = (NN + BM - 1) / BM, NT = N / BN, GB = MT * NT;
    __shared__ ushort sA[BM * BK];
    __shared__ ushort sB[BN * BK];
    const int kb = blockIdx.x / GB;
    const int bid = blockIdx.x % GB;
    const ushort* Ab = A + (size_t)kb * aBatch;
    const ushort* BT = BTall + (size_t)kb * btBatch;
    const float* dinv = dinv3 + (size_t)kb * NN;
    ushort* C = Call + (size_t)kb * cBatch;
    const int t = threadIdx.x, lane = t & 63, wid = t >> 6;
    const int wm = (wid / WGN) * 64, wn = (wid % WGN) * 64;
    const int bm = (bid / NT) * BM;
    const int bn = (bid % NT) * BN;

    f32x4 zero = {0.f, 0.f, 0.f, 0.f};
    f32x4 acc[4][4];
#pragma unroll
    for (int m = 0; m < 4; ++m)
#pragma unroll
        for (int n = 0; n < 4; ++n) acc[m][n] = zero;

    constexpr int A_ISS = (BM * BK * 2) / (NW * 1024);
    constexpr int B_ISS = (BN * BK * 2) / (NW * 1024);

    for (int kt = 0; kt < KK; kt += BK) {
        const int akt = (kt >= AK) ? kt - AK : kt;
        __syncthreads();
#pragma unroll
        for (int i = 0; i < A_ISS; ++i) {
            int off = (wid + i * NW) << 10;
            int la = off + lane * 16;
            int row = la >> 6;
            int slot = (la >> 4) & 3;
            int scol = (slot ^ (row & 3)) << 4;
            int grow = bm + row;
            if (grow > NN - 1) grow = NN - 1;
            const char* ga = (const char*)Ab + (size_t)grow * (AK * 2) + akt * 2 + scol;
            __builtin_amdgcn_global_load_lds(
                (__attribute__((address_space(1))) const void*)ga,
                (__attribute__((address_space(3))) void*)((char*)sA + off), 16, 0, 0);
        }
#pragma unroll
        for (int i = 0; i < B_ISS; ++i) {
            int off = (wid + i * NW) << 10;
            int la = off + lane * 16;
            int row = la >> 6;
            int slot = (la >> 4) & 3;
            int scol = (slot ^ (row & 3)) << 4;
            const char* ga = (const char*)BT + (size_t)(bn + row) * (KK * 2) + kt * 2 + scol;
            __builtin_amdgcn_global_load_lds(
                (__attribute__((address_space(1))) const void*)ga,
                (__attribute__((address_space(3))) void*)((char*)sB + off), 16, 0, 0);
        }
        __syncthreads();

        const int s = lane >> 4;
        const int r0 = lane & 15;
        short8 af[4], bf[4];
#pragma unroll
        for (int m = 0; m < 4; ++m) {
            int row = wm + m * 16 + r0;
            af[m] = *(const short8*)((const char*)sA + row * 64 + ((s ^ (row & 3)) << 4));
        }
#pragma unroll
        for (int n = 0; n < 4; ++n) {
            int row = wn + n * 16 + r0;
            bf[n] = *(const short8*)((const char*)sB + row * 64 + ((s ^ (row & 3)) << 4));
        }
#pragma unroll
        for (int m = 0; m < 4; ++m)
#pragma unroll
            for (int n = 0; n < 4; ++n) {
                if constexpr (HALF)
                    acc[m][n] = __builtin_amdgcn_mfma_f32_16x16x32_f16(
                        __builtin_bit_cast(half8, af[m]), __builtin_bit_cast(half8, bf[n]),
                        acc[m][n], 0, 0, 0);
                else
                    acc[m][n] = __builtin_amdgcn_mfma_f32_16x16x32_bf16(af[m], bf[n],
                                                                        acc[m][n], 0, 0, 0);
            }
    }

    const int cr0 = (lane >> 4) * 4;
    const int cc = lane & 15;
#pragma unroll
    for (int m = 0; m < 4; ++m) {
#pragma unroll
        for (int r = 0; r < 4; ++r) {
            int row = bm + wm + m * 16 + cr0 + r;
            if (row < NN) {
                float dv = dinv[row];
#pragma unroll
                for (int n = 0; n < 4; ++n)
                    C[(size_t)row * N + bn + wn + n * 16 + cc] = f2h(acc[m][n][r] * dv);
            }
        }
    }
}

// ---------------- layer-1 aggregation (batched over 3 branches) ----------------

__global__ __launch_bounds__(256) void k_agg1(const ushort* __restrict__ hs16all,
                                              const int* __restrict__ seg3,
                                              const int* __restrict__ cnt3,
                                              const ushort* __restrict__ g_csr,
                                              const float* __restrict__ dinv3,
                                              const float* __restrict__ b1a,
                                              const float* __restrict__ b1b,
                                              const float* __restrict__ b1c,
                                              ushort* __restrict__ h1all) {
    constexpr int WBn = (NN + 3) / 4;
    const int b = blockIdx.x / WBn;
    const int blk = blockIdx.x % WBn;
    const int wid = threadIdx.x >> 6;
    const int lane = threadIdx.x & 63;
    const int node = blk * 4 + wid;
    if (node >= NN) return;
    const int half = lane >> 5, l32 = lane & 31;
    const int g = b * NN + node;
    const ushort* hs = hs16all + (size_t)b * NN * 256;
    const ushort* csr = g_csr + seg3[g];
    const int len = cnt3[g] + 1;
    const size_t colb = (size_t)l32 * 8;

    float acc[8] = {0.f, 0.f, 0.f, 0.f, 0.f, 0.f, 0.f, 0.f};
    int i = half;
    for (; i + 6 < len; i += 8) {
        int s0 = (i == 0) ? node : (int)csr[i - 1];
        int s1 = (int)csr[i + 1];
        int s2 = (int)csr[i + 3];
        int s3 = (int)csr[i + 5];
        ushort8v v0 = *(const ushort8v*)&hs[(size_t)s0 * 256 + colb];
        ushort8v v1 = *(const ushort8v*)&hs[(size_t)s1 * 256 + colb];
        ushort8v v2 = *(const ushort8v*)&hs[(size_t)s2 * 256 + colb];
        ushort8v v3 = *(const ushort8v*)&hs[(size_t)s3 * 256 + colb];
#pragma unroll
        for (int j = 0; j < 8; ++j)
            acc[j] += (h2f(v0[j]) + h2f(v1[j])) + (h2f(v2[j]) + h2f(v3[j]));
    }
    for (; i < len; i += 2) {
        int s = (i == 0) ? node : (int)csr[i - 1];
        ushort8v v = *(const ushort8v*)&hs[(size_t)s * 256 + colb];
#pragma unroll
        for (int j = 0; j < 8; ++j) acc[j] += h2f(v[j]);
    }
#pragma unroll
    for (int j = 0; j < 8; ++j) acc[j] += __shfl_xor(acc[j], 32);

    if (half == 0) {
        const float* bias = (b == 0 ? b1a : b == 1 ? b1b : b1c);
        const float di = dinv3[g];
        ushort8v o;
#pragma unroll
        for (int j = 0; j < 8; ++j) {
            float r = fmaxf(di * acc[j] + bias[l32 * 8 + j], 0.f);
            o[j] = f2h(r);
        }
        *(ushort8v*)&h1all[((size_t)b * NN + node) * 256 + colb] = o;
    }
}

// ---------------- fused layer-2 aggregation (x3) + attention ----------------

__global__ __launch_bounds__(256) void k_final(const ushort* __restrict__ hs2all,
                                               const int* __restrict__ seg3,
                                               const int* __restrict__ cnt3,
                                               const ushort* __restrict__ g_csr,
                                               const float* __restrict__ dinv3,
                                               const float* __restrict__ b2a,
                                               const float* __restrict__ b2b,
                                               const float* __restrict__ b2c,
                                               const float* __restrict__ attn_w,
                                               const float* __restrict__ attn_b,
                                               float* __restrict__ out) {
    const int wid = threadIdx.x >> 6;
    const int lane = threadIdx.x & 63;
    const int node = blockIdx.x * 4 + wid;
    if (node >= NN) return;
    const int half = lane >> 5, l32 = lane & 31;
    const size_t colb = (size_t)l32 * 4;

    float f[3][4];
#pragma unroll
    for (int b = 0; b < 3; ++b) {
        const int g = b * NN + node;
        const ushort* hs = hs2all + (size_t)b * NN * 128;
        const ushort* csr = g_csr + seg3[g];
        const int len = cnt3[g] + 1;
        float acc[4] = {0.f, 0.f, 0.f, 0.f};
        int i = half;
        for (; i + 6 < len; i += 8) {
            int s0 = (i == 0) ? node : (int)csr[i - 1];
            int s1 = (int)csr[i + 1];
            int s2 = (int)csr[i + 3];
            int s3 = (int)csr[i + 5];
            ushort4v v0 = *(const ushort4v*)&hs[(size_t)s0 * 128 + colb];
            ushort4v v1 = *(const ushort4v*)&hs[(size_t)s1 * 128 + colb];
            ushort4v v2 = *(const ushort4v*)&hs[(size_t)s2 * 128 + colb];
            ushort4v v3 = *(const ushort4v*)&hs[(size_t)s3 * 128 + colb];
#pragma unroll
            for (int j = 0; j < 4; ++j)
                acc[j] += (h2f(v0[j]) + h2f(v1[j])) + (h2f(v2[j]) + h2f(v3[j]));
        }
        for (; i < len; i += 2) {
            int s = (i == 0) ? node : (int)csr[i - 1];
            ushort4v v = *(const ushort4v*)&hs[(size_t)s * 128 + colb];
#pragma unroll
            for (int j = 0; j < 4; ++j) acc[j] += h2f(v[j]);
        }
#pragma unroll
        for (int j = 0; j < 4; ++j) acc[j] += __shfl_xor(acc[j], 32);
        const float* bias = (b == 0 ? b2a : b == 1 ? b2b : b2c);
        const float di = dinv3[g];
#pragma unroll
        for (int j = 0; j < 4; ++j) f[b][j] = di * acc[j] + bias[l32 * 4 + j];
    }

    float4 w = *(const float4*)&attn_w[l32 * 4];
    float s0 = f[0][0] * w.x + f[0][1] * w.y + f[0][2] * w.z + f[0][3] * w.w;
    float s1 = f[1][0] * w.x + f[1][1] * w.y + f[1][2] * w.z + f[1][3] * w.w;
    float s2 = f[2][0] * w.x + f[2][1] * w.y + f[2][2] * w.z + f[2][3] * w.w;
#pragma unroll
    for (int m = 16; m >= 1; m >>= 1) {
        s0 += __shfl_xor(s0, m);
        s1 += __shfl_xor(s1, m);
        s2 += __shfl_xor(s2, m);
    }
    float bb = attn_b[0];
    s0 += bb; s1 += bb; s2 += bb;
    float mx = fmaxf(s0, fmaxf(s1, s2));
    float e0 = expf(s0 - mx), e1 = expf(s1 - mx), e2 = expf(s2 - mx);
    float inv = 1.f / (e0 + e1 + e2);
    e0 *= inv; e1 *= inv; e2 *= inv;

    if (half == 0) {
        float4 o;
        o.x = f[0][0] * e0 + f[1][0] * e1 + f[2][0] * e2;
        o.y = f[0][1] * e0 + f[1][1] * e1 + f[2][1] * e2;
        o.z = f[0][2] * e0 + f[1][2] * e1 + f[2][2] * e2;
        o.w = f[0][3] * e0 + f[1][3] * e1 + f[2][3] * e2;
        *(float4*)&out[(size_t)node * 128 + colb] = o;
    }
}

// ---------------- launch ----------------

extern "C" void kernel_launch(void* const* d_in, const int* in_sizes, int n_in,
                              void* d_out, int out_size, void* d_ws, size_t ws_size,
                              hipStream_t stream) {
    const float* x = (const float*)d_in[0];
    const int* e0 = (const int*)d_in[1];
    const int* e1 = (const int*)d_in[2];
    const int* e2 = (const int*)d_in[3];
    const float* attn_w = (const float*)d_in[16];
    const float* attn_b = (const float*)d_in[17];

    char* ws = (char*)d_ws;
    size_t off = 0;
    auto alloc = [&](size_t bytes) -> void* {
        void* p = ws + off;
        off += (bytes + 255) & ~(size_t)255;
        return p;
    };

    int* g_cur      = (int*)alloc(3 * BINS * 4);                 // zeroed
    int* seg3       = (int*)alloc((size_t)3 * NN * 4);
    int* cnt3       = (int*)alloc((size_t)3 * NN * 4);
    float* dinv3    = (float*)alloc((size_t)3 * NN * 4);
    ushort* g_csr   = (ushort*)alloc((size_t)3 * BINS * CAP * 2);  // 7.2 MB
    ushort* xp      = (ushort*)alloc((size_t)NN * 512 * 2);       // 51.2 MB
    ushort* hs2all  = xp;  // alias: xp dead after gemm1; hs2 (38.4 MB) fits
    ushort* hs16all = (ushort*)alloc((size_t)3 * NN * 256 * 2);   // 76.8 MB
    ushort* h1all   = (ushort*)alloc((size_t)3 * NN * 256 * 2);   // 76.8 MB
    unsigned* g_bins = (unsigned*)h1all;  // alias: g_bins dead before h1all written
    ushort* BT1all  = (ushort*)alloc((size_t)3 * 256 * 768 * 2);
    ushort* BT2all  = (ushort*)alloc((size_t)3 * 128 * 256 * 2);

    const int WB = (NN + 3) / 4;  // 12500

    hipMemsetAsync(g_cur, 0, 3 * BINS * 4, stream);
    k_conv_x<<<WB, 256, 0, stream>>>(x, xp);
    k_conv_w1<<<768, 256, 0, stream>>>((const float*)d_in[4], (const float*)d_in[8],
                                       (const float*)d_in[12], BT1all);
    k_conv_w2<<<384, 256, 0, stream>>>((const float*)d_in[6], (const float*)d_in[10],
                                       (const float*)d_in[14], BT2all);

    k_bin<<<3 * P1B, 256, 0, stream>>>(e0, e1, e2, g_cur, g_bins);
    k_build<<<3 * BINS, 256, 0, stream>>>(g_bins, g_cur, g_csr, seg3, cnt3, dinv3);

    // layer 1: hs = dinv*(x @ W1) bf16x3 -> fp16, all branches
    k_gemm<128, 128, 256, 768, 512, false><<<3 * 391 * 2, 256, 0, stream>>>(
        xp, 0, BT1all, 196608, dinv3, hs16all, (size_t)NN * 256);
    k_agg1<<<3 * WB, 256, 0, stream>>>(hs16all, seg3, cnt3, g_csr, dinv3,
                                       (const float*)d_in[5], (const float*)d_in[9],
                                       (const float*)d_in[13], h1all);

    // layer 2: hs2 = dinv*(h1 @ W2) fp16, all branches
    k_gemm<128, 128, 128, 256, 256, true><<<3 * 391, 256, 0, stream>>>(
        h1all, (size_t)NN * 256, BT2all, 32768, dinv3, hs2all, (size_t)NN * 128);

    // fused layer-2 aggregation + attention
    k_final<<<WB, 256, 0, stream>>>(hs2all, seg3, cnt3, g_csr, dinv3,
                                    (const float*)d_in[7], (const float*)d_in[11],
                                    (const float*)d_in[15], attn_w, attn_b,
                                    (float*)d_out);
}